// Round 1
// baseline (3723.956 us; speedup 1.0000x reference)
//
#include <hip/hip_runtime.h>
#include <hip/hip_bf16.h>
#include <math.h>

#define N_NODES 50000
#define N_EDGES 800000
#define N_GRAPHS 64
#define E2_TOTAL (N_EDGES + N_NODES)

// ---------------------------------------------------------------- CSR build

__global__ __launch_bounds__(256) void deg_kernel(const int* __restrict__ ei,
                                                  const float* __restrict__ eattr,
                                                  int* __restrict__ deg,
                                                  float* __restrict__ asum, int E) {
    int e = blockIdx.x * 256 + threadIdx.x;
    if (e >= E) return;
    int dst = ei[E + e];
    atomicAdd(&deg[dst], 1);
    atomicAdd(&asum[dst * 3 + 0], eattr[e * 3 + 0]);
    atomicAdd(&asum[dst * 3 + 1], eattr[e * 3 + 1]);
    atomicAdd(&asum[dst * 3 + 2], eattr[e * 3 + 2]);
}

__global__ __launch_bounds__(256) void loopattr_kernel(const int* __restrict__ deg,
                                                       float* __restrict__ asum, int N) {
    int n = blockIdx.x * 256 + threadIdx.x;
    if (n >= N) return;
    float inv = 1.0f / (float)max(deg[n], 1);
    asum[n * 3 + 0] *= inv;
    asum[n * 3 + 1] *= inv;
    asum[n * 3 + 2] *= inv;
}

// exclusive scan of (deg[n]+1), single block of 1024 threads
__global__ __launch_bounds__(1024) void scan_kernel(const int* __restrict__ deg,
                                                    int* __restrict__ rowptr, int N) {
    __shared__ int wsum[16];
    __shared__ int carry_s;
    int tid = threadIdx.x, lane = tid & 63, wid = tid >> 6;
    if (tid == 0) carry_s = 0;
    __syncthreads();
    for (int base = 0; base < N; base += 1024) {
        int idx = base + tid;
        int v = (idx < N) ? deg[idx] + 1 : 0;
        int x = v;
        #pragma unroll
        for (int off = 1; off < 64; off <<= 1) {
            int t = __shfl_up(x, off);
            if (lane >= off) x += t;
        }
        if (lane == 63) wsum[wid] = x;
        __syncthreads();
        if (wid == 0) {
            int y = (lane < 16) ? wsum[lane] : 0;
            #pragma unroll
            for (int off = 1; off < 16; off <<= 1) {
                int t = __shfl_up(y, off);
                if (lane >= off) y += t;
            }
            if (lane < 16) wsum[lane] = y;
        }
        __syncthreads();
        int woff = (wid > 0) ? wsum[wid - 1] : 0;
        int incl = carry_s + woff + x;
        if (idx < N) rowptr[idx] = incl - v;  // exclusive
        __syncthreads();
        if (tid == 1023) carry_s += wsum[15];
        __syncthreads();
    }
    if (threadIdx.x == 0) rowptr[N] = carry_s;
}

__global__ __launch_bounds__(256) void copy_kernel(const int* __restrict__ a,
                                                   int* __restrict__ b, int N) {
    int n = blockIdx.x * 256 + threadIdx.x;
    if (n < N) b[n] = a[n];
}

__global__ __launch_bounds__(256) void fill_kernel(const int* __restrict__ ei,
                                                   int* __restrict__ cursor,
                                                   int* __restrict__ csr_src,
                                                   int* __restrict__ csr_eid,
                                                   int E, int E2) {
    int e = blockIdx.x * 256 + threadIdx.x;
    if (e >= E2) return;
    int src, dst;
    if (e < E) { src = ei[e]; dst = ei[E + e]; }
    else       { src = e - E; dst = e - E; }
    int pos = atomicAdd(&cursor[dst], 1);
    csr_src[pos] = src;
    csr_eid[pos] = e;
}

// ---------------------------------------------------------------- GEMM (fp32)
// Y[N,M] = A[N,K] @ W[K,M] + bias ; 128x128 tile, BK=8, 256 thr, 8x8/thread

__global__ __launch_bounds__(256) void gemm_bias(const float* __restrict__ A,
                                                 const float* __restrict__ W,
                                                 const float* __restrict__ bias,
                                                 float* __restrict__ Y,
                                                 int N, int K, int M) {
    __shared__ float As[8][132];
    __shared__ float Ws[8][132];
    int tid = threadIdx.x;
    int bm = blockIdx.x * 128, bn = blockIdx.y * 128;
    int tx = tid & 15, ty = tid >> 4;
    float acc[8][8] = {};
    int a_m = tid >> 1, a_k = (tid & 1) * 4;
    int w_k = tid >> 5, w_n = (tid & 31) * 4;
    for (int k0 = 0; k0 < K; k0 += 8) {
        int row = bm + a_m;
        float4 av = make_float4(0.f, 0.f, 0.f, 0.f);
        if (row < N) av = *reinterpret_cast<const float4*>(A + (size_t)row * K + k0 + a_k);
        As[a_k + 0][a_m] = av.x; As[a_k + 1][a_m] = av.y;
        As[a_k + 2][a_m] = av.z; As[a_k + 3][a_m] = av.w;
        float4 wv = *reinterpret_cast<const float4*>(W + (size_t)(k0 + w_k) * M + bn + w_n);
        *reinterpret_cast<float4*>(&Ws[w_k][w_n]) = wv;
        __syncthreads();
        #pragma unroll
        for (int k = 0; k < 8; k++) {
            float4 a0 = *reinterpret_cast<float4*>(&As[k][ty * 8]);
            float4 a1 = *reinterpret_cast<float4*>(&As[k][ty * 8 + 4]);
            float4 w0 = *reinterpret_cast<float4*>(&Ws[k][tx * 8]);
            float4 w1 = *reinterpret_cast<float4*>(&Ws[k][tx * 8 + 4]);
            float a[8] = {a0.x, a0.y, a0.z, a0.w, a1.x, a1.y, a1.z, a1.w};
            float b[8] = {w0.x, w0.y, w0.z, w0.w, w1.x, w1.y, w1.z, w1.w};
            #pragma unroll
            for (int i = 0; i < 8; i++)
                #pragma unroll
                for (int j = 0; j < 8; j++) acc[i][j] += a[i] * b[j];
        }
        __syncthreads();
    }
    #pragma unroll
    for (int i = 0; i < 8; i++) {
        int row = bm + ty * 8 + i;
        if (row < N) {
            #pragma unroll
            for (int j = 0; j < 8; j++) {
                int col = bn + tx * 8 + j;
                Y[(size_t)row * M + col] = acc[i][j] + bias[col];
            }
        }
    }
}

// ---------------------------------------------------------------- attention

// one 64-lane wave per CSR slot; computes logits for all H heads of that edge
template <int HC, bool L1>
__global__ __launch_bounds__(256) void attn_logits(
    const int* __restrict__ csr_src, const int* __restrict__ csr_eid,
    const int* __restrict__ ei, const float* __restrict__ eattr,
    const float* __restrict__ lattr,
    const float* __restrict__ XL, const float* __restrict__ XR,
    const float* __restrict__ x8, const float* __restrict__ Wl,
    const float* __restrict__ bl, const float* __restrict__ Wr,
    const float* __restrict__ br,
    const float* __restrict__ We, const float* __restrict__ att,
    float* __restrict__ logits, int E, int E2) {
    constexpr int H = HC / 128;
    int j = (blockIdx.x * 256 + threadIdx.x) >> 6;
    int lane = threadIdx.x & 63;
    if (j >= E2) return;
    int eid = csr_eid[j];
    int src = csr_src[j];
    int dst;
    const float* ea;
    if (eid < E) { dst = ei[E + eid]; ea = eattr + (size_t)eid * 3; }
    else         { dst = eid - E;     ea = lattr + (size_t)dst * 3; }
    float ea0 = ea[0], ea1 = ea[1], ea2 = ea[2];
    float xs[8], xd[8];
    if (L1) {
        #pragma unroll
        for (int k = 0; k < 8; k++) { xs[k] = x8[src * 8 + k]; xd[k] = x8[dst * 8 + k]; }
    }
    float hsum[H];
    #pragma unroll
    for (int h = 0; h < H; h++) hsum[h] = 0.f;
    #pragma unroll
    for (int k = 0; k < HC / 64; k++) {
        int i = k * 64 + lane;
        float xl_i, xr_i;
        if (L1) {
            xl_i = bl[i]; xr_i = br[i];
            #pragma unroll
            for (int kk = 0; kk < 8; kk++) {
                xl_i += xs[kk] * Wl[kk * HC + i];
                xr_i += xd[kk] * Wr[kk * HC + i];
            }
        } else {
            xl_i = XL[(size_t)src * HC + i];
            xr_i = XR[(size_t)dst * HC + i];
        }
        float ee = ea0 * We[i] + ea1 * We[HC + i] + ea2 * We[2 * HC + i];
        float u = xl_i + xr_i + ee;
        float lr = u > 0.f ? u : 0.2f * u;
        hsum[k >> 1] += lr * att[i];
    }
    #pragma unroll
    for (int h = 0; h < H; h++) {
        float v = hsum[h];
        #pragma unroll
        for (int off = 32; off; off >>= 1) v += __shfl_xor(v, off);
        if (lane == 0) logits[(size_t)j * H + h] = v;
    }
}

// one block (256 thr) per dst node: segment softmax + weighted aggregation
template <int HC, bool L1>
__global__ __launch_bounds__(256) void attn_aggregate(
    const int* __restrict__ rowptr, const int* __restrict__ csr_src,
    const float* __restrict__ logits, const float* __restrict__ XL,
    const float* __restrict__ x8, const float* __restrict__ Wl,
    const float* __restrict__ bl, const float* __restrict__ bo,
    float* __restrict__ out, int N) {
    constexpr int H = HC / 128;
    constexpr int CH = 64;
    int n = blockIdx.x;
    int tid = threadIdx.x;
    __shared__ float red[256];
    __shared__ float sm[H], sinv[H];
    __shared__ int s_src[CH];
    __shared__ float s_w[CH * H];
    __shared__ float s_x[L1 ? CH * 8 : 1];
    __shared__ float sWl[L1 ? 8 * HC : 1];
    __shared__ float sbl[L1 ? HC : 1];
    if (L1) {
        for (int i = tid; i < 8 * HC; i += 256) sWl[i] = Wl[i];
        for (int i = tid; i < HC; i += 256) sbl[i] = bl[i];
    }
    int beg = rowptr[n], end = rowptr[n + 1];
    // phase 1: per-head max & sum-exp
    for (int h = 0; h < H; h++) {
        float lm = -INFINITY;
        for (int j = beg + tid; j < end; j += 256)
            lm = fmaxf(lm, logits[(size_t)j * H + h]);
        red[tid] = lm; __syncthreads();
        for (int s = 128; s; s >>= 1) {
            if (tid < s) red[tid] = fmaxf(red[tid], red[tid + s]);
            __syncthreads();
        }
        float bm = red[0]; __syncthreads();
        float ls = 0.f;
        for (int j = beg + tid; j < end; j += 256)
            ls += expf(logits[(size_t)j * H + h] - bm);
        red[tid] = ls; __syncthreads();
        for (int s = 128; s; s >>= 1) {
            if (tid < s) red[tid] += red[tid + s];
            __syncthreads();
        }
        if (tid == 0) { sm[h] = bm; sinv[h] = 1.f / (red[0] + 1e-16f); }
        __syncthreads();
    }
    // phase 2: chunked weighted aggregation
    constexpr int PT = (HC + 255) / 256;
    float acc[PT];
    #pragma unroll
    for (int p = 0; p < PT; p++) acc[p] = 0.f;
    for (int jb = beg; jb < end; jb += CH) {
        int nc = min(CH, end - jb);
        if (tid < nc) {
            int s = csr_src[jb + tid];
            s_src[tid] = s;
            #pragma unroll
            for (int h = 0; h < H; h++)
                s_w[tid * H + h] = expf(logits[(size_t)(jb + tid) * H + h] - sm[h]) * sinv[h];
        }
        __syncthreads();
        if (L1) {
            for (int i = tid; i < nc * 8; i += 256)
                s_x[i] = x8[(size_t)s_src[i >> 3] * 8 + (i & 7)];
            __syncthreads();
        }
        #pragma unroll
        for (int p = 0; p < PT; p++) {
            int i = tid + p * 256;
            if (i < HC) {
                int h = i >> 7;
                float a = acc[p];
                for (int jj = 0; jj < nc; jj++) {
                    float w = s_w[jj * H + h];
                    float xv;
                    if (L1) {
                        float v = sbl[i];
                        #pragma unroll
                        for (int kk = 0; kk < 8; kk++) v += s_x[jj * 8 + kk] * sWl[kk * HC + i];
                        xv = v;
                    } else {
                        xv = XL[(size_t)s_src[jj] * HC + i];
                    }
                    a += w * xv;
                }
                acc[p] = a;
            }
        }
        __syncthreads();
    }
    #pragma unroll
    for (int p = 0; p < PT; p++) {
        int i = tid + p * 256;
        if (i < HC) out[(size_t)n * HC + i] = acc[p] + bo[i];
    }
}

// ---------------------------------------------------------------- layernorm

__global__ __launch_bounds__(256) void ln_stats(const float* __restrict__ x,
                                                double* __restrict__ stats, size_t count) {
    double s = 0.0, s2 = 0.0;
    for (size_t i = (size_t)blockIdx.x * 256 + threadIdx.x; i < count;
         i += (size_t)gridDim.x * 256) {
        double v = (double)x[i];
        s += v; s2 += v * v;
    }
    #pragma unroll
    for (int off = 32; off; off >>= 1) {
        s += __shfl_xor(s, off);
        s2 += __shfl_xor(s2, off);
    }
    __shared__ double wsh[4], wsh2[4];
    int wid = threadIdx.x >> 6, lane = threadIdx.x & 63;
    if (lane == 0) { wsh[wid] = s; wsh2[wid] = s2; }
    __syncthreads();
    if (threadIdx.x == 0) {
        double a = 0.0, b = 0.0;
        for (int w = 0; w < 4; w++) { a += wsh[w]; b += wsh2[w]; }
        atomicAdd(&stats[0], a);
        atomicAdd(&stats[1], b);
    }
}

__global__ __launch_bounds__(256) void ln_apply_elu(float* __restrict__ x,
                                                    const double* __restrict__ stats,
                                                    const float* __restrict__ w,
                                                    const float* __restrict__ b,
                                                    int F, size_t count) {
    double mu = stats[0] / (double)count;
    double var = stats[1] / (double)count - mu * mu;
    float sd = (float)sqrt(var > 0.0 ? var : 0.0);
    float rs = 1.f / (sd + 1e-5f);
    float muf = (float)mu;
    for (size_t i = (size_t)blockIdx.x * 256 + threadIdx.x; i < count;
         i += (size_t)gridDim.x * 256) {
        int c = (int)(i & (size_t)(F - 1));
        float v = (x[i] - muf) * rs * w[c] + b[c];
        x[i] = v > 0.f ? v : expm1f(v);
    }
}

// ---------------------------------------------------------------- pooling

__global__ __launch_bounds__(256) void gcnt_kernel(const int* __restrict__ batch,
                                                   int* __restrict__ gcnt, int N) {
    int n = blockIdx.x * 256 + threadIdx.x;
    if (n < N) atomicAdd(&gcnt[batch[n]], 1);
}

__global__ __launch_bounds__(256) void pool_accum(const float* __restrict__ h,
                                                  const int* __restrict__ batch,
                                                  float* __restrict__ macc,
                                                  unsigned* __restrict__ mxb, int N) {
    int idx = blockIdx.x * 256 + threadIdx.x;
    if (idx >= N * 128) return;
    int n = idx >> 7, c = idx & 127;
    int g = batch[n];
    float v = h[(size_t)n * 128 + c];
    atomicAdd(&macc[g * 128 + c], v);
    unsigned u = __float_as_uint(v);
    u = (u & 0x80000000u) ? ~u : (u | 0x80000000u);
    atomicMax(&mxb[g * 128 + c], u);
}

__global__ __launch_bounds__(256) void pool_write(const float* __restrict__ macc,
                                                  const unsigned* __restrict__ mxb,
                                                  const int* __restrict__ gcnt,
                                                  float* __restrict__ out) {
    int idx = blockIdx.x * 256 + threadIdx.x;
    if (idx >= N_GRAPHS * 128) return;
    int g = idx >> 7, c = idx & 127;
    int cnt = gcnt[g];
    float mean = macc[idx] / (float)max(cnt, 1);
    float mx = 0.f;
    if (cnt > 0) {
        unsigned u = mxb[idx];
        mx = __uint_as_float((u & 0x80000000u) ? (u ^ 0x80000000u) : ~u);
    }
    out[g * 256 + c] = mean;
    out[g * 256 + 128 + c] = mx;
}

// ---------------------------------------------------------------- launch

extern "C" void kernel_launch(void* const* d_in, const int* in_sizes, int n_in,
                              void* d_out, int out_size, void* d_ws, size_t ws_size,
                              hipStream_t stream) {
    const int N = N_NODES, E = N_EDGES, G = N_GRAPHS, E2 = E2_TOTAL;
    const float* x = (const float*)d_in[0];
    const int* ei = (const int*)d_in[1];
    const float* eattr = (const float*)d_in[2];
    const int* batch = (const int*)d_in[3];
    auto P = [&](int l, int k) { return (const float*)d_in[4 + l * 9 + k]; };
    // k: 0=Wl 1=bl 2=Wr 3=br 4=We 5=att 6=bo 7=lnw 8=lnb

    char* w = (char*)d_ws;
    size_t off = 0;
    auto alloc = [&](size_t bytes) -> void* {
        void* p = w + off;
        off += (bytes + 255) & ~(size_t)255;
        return p;
    };
    float* B0 = (float*)alloc((size_t)N * 512 * 4);
    float* B1 = (float*)alloc((size_t)N * 256 * 4);
    float* B2 = (float*)alloc((size_t)N * 256 * 4);
    float* logits = (float*)alloc((size_t)E2 * 4 * 4);
    int* csr_src = (int*)alloc((size_t)E2 * 4);
    int* csr_eid = (int*)alloc((size_t)E2 * 4);
    int* rowptr = (int*)alloc((size_t)(N + 1) * 4);
    int* cursor = (int*)alloc((size_t)N * 4);
    int* deg = (int*)alloc((size_t)N * 4);
    float* lattr = (float*)alloc((size_t)N * 3 * 4);
    double* stats = (double*)alloc(6 * 8);
    float* macc = (float*)alloc((size_t)G * 128 * 4);
    unsigned* mxb = (unsigned*)alloc((size_t)G * 128 * 4);
    int* gcnt = (int*)alloc((size_t)G * 4);
    (void)ws_size; (void)n_in; (void)in_sizes; (void)out_size;

    hipMemsetAsync(deg, 0, (size_t)N * 4, stream);
    hipMemsetAsync(lattr, 0, (size_t)N * 3 * 4, stream);
    hipMemsetAsync(stats, 0, 6 * 8, stream);
    hipMemsetAsync(macc, 0, (size_t)G * 128 * 4, stream);
    hipMemsetAsync(mxb, 0, (size_t)G * 128 * 4, stream);
    hipMemsetAsync(gcnt, 0, (size_t)G * 4, stream);

    deg_kernel<<<(E + 255) / 256, 256, 0, stream>>>(ei, eattr, deg, lattr, E);
    loopattr_kernel<<<(N + 255) / 256, 256, 0, stream>>>(deg, lattr, N);
    scan_kernel<<<1, 1024, 0, stream>>>(deg, rowptr, N);
    copy_kernel<<<(N + 255) / 256, 256, 0, stream>>>(rowptr, cursor, N);
    fill_kernel<<<(E2 + 255) / 256, 256, 0, stream>>>(ei, cursor, csr_src, csr_eid, E, E2);

    int ablk = (E2 + 3) / 4;

    // -------- layer 1 (din=8, H=4, HC=512): xl/xr recomputed on the fly
    attn_logits<512, true><<<ablk, 256, 0, stream>>>(
        csr_src, csr_eid, ei, eattr, lattr, nullptr, nullptr,
        x, P(0, 0), P(0, 1), P(0, 2), P(0, 3), P(0, 4), P(0, 5), logits, E, E2);
    attn_aggregate<512, true><<<N, 256, 0, stream>>>(
        rowptr, csr_src, logits, nullptr, x, P(0, 0), P(0, 1), P(0, 6), B0, N);
    ln_stats<<<2048, 256, 0, stream>>>(B0, stats + 0, (size_t)N * 512);
    ln_apply_elu<<<2048, 256, 0, stream>>>(B0, stats + 0, P(0, 7), P(0, 8), 512,
                                           (size_t)N * 512);

    // -------- layer 2 (din=512, H=2, HC=256)
    {
        dim3 g((N + 127) / 128, 256 / 128);
        gemm_bias<<<g, 256, 0, stream>>>(B0, P(1, 0), P(1, 1), B1, N, 512, 256);
        gemm_bias<<<g, 256, 0, stream>>>(B0, P(1, 2), P(1, 3), B2, N, 512, 256);
    }
    attn_logits<256, false><<<ablk, 256, 0, stream>>>(
        csr_src, csr_eid, ei, eattr, lattr, B1, B2,
        nullptr, nullptr, nullptr, nullptr, nullptr, P(1, 4), P(1, 5), logits, E, E2);
    attn_aggregate<256, false><<<N, 256, 0, stream>>>(
        rowptr, csr_src, logits, B1, nullptr, nullptr, nullptr, P(1, 6), B0, N);
    ln_stats<<<2048, 256, 0, stream>>>(B0, stats + 2, (size_t)N * 256);
    ln_apply_elu<<<2048, 256, 0, stream>>>(B0, stats + 2, P(1, 7), P(1, 8), 256,
                                           (size_t)N * 256);

    // -------- layer 3 (din=256, H=1, HC=128)
    {
        dim3 g((N + 127) / 128, 1);
        gemm_bias<<<g, 256, 0, stream>>>(B0, P(2, 0), P(2, 1), B1, N, 256, 128);
        gemm_bias<<<g, 256, 0, stream>>>(B0, P(2, 2), P(2, 3), B2, N, 256, 128);
    }
    attn_logits<128, false><<<ablk, 256, 0, stream>>>(
        csr_src, csr_eid, ei, eattr, lattr, B1, B2,
        nullptr, nullptr, nullptr, nullptr, nullptr, P(2, 4), P(2, 5), logits, E, E2);
    attn_aggregate<128, false><<<N, 256, 0, stream>>>(
        rowptr, csr_src, logits, B1, nullptr, nullptr, nullptr, P(2, 6), B0, N);
    ln_stats<<<2048, 256, 0, stream>>>(B0, stats + 4, (size_t)N * 128);
    ln_apply_elu<<<2048, 256, 0, stream>>>(B0, stats + 4, P(2, 7), P(2, 8), 128,
                                           (size_t)N * 128);

    // -------- pooling
    gcnt_kernel<<<(N + 255) / 256, 256, 0, stream>>>(batch, gcnt, N);
    pool_accum<<<(N * 128 + 255) / 256, 256, 0, stream>>>(B0, batch, macc, mxb, N);
    pool_write<<<(G * 128 + 255) / 256, 256, 0, stream>>>(macc, mxb, gcnt,
                                                          (float*)d_out);
}

// Round 2
// 3004.255 us; speedup vs baseline: 1.2396x; 1.2396x over previous
//
#include <hip/hip_runtime.h>
#include <hip/hip_bf16.h>
#include <math.h>

#define N_NODES 50000
#define N_EDGES 800000
#define N_GRAPHS 64
#define E2_TOTAL (N_EDGES + N_NODES)

// ---------------------------------------------------------------- CSR build

__global__ __launch_bounds__(256) void deg_kernel(const int* __restrict__ ei,
                                                  const float* __restrict__ eattr,
                                                  int* __restrict__ deg,
                                                  float* __restrict__ asum, int E) {
    int e = blockIdx.x * 256 + threadIdx.x;
    if (e >= E) return;
    int dst = ei[E + e];
    atomicAdd(&deg[dst], 1);
    atomicAdd(&asum[dst * 3 + 0], eattr[e * 3 + 0]);
    atomicAdd(&asum[dst * 3 + 1], eattr[e * 3 + 1]);
    atomicAdd(&asum[dst * 3 + 2], eattr[e * 3 + 2]);
}

__global__ __launch_bounds__(256) void loopattr_kernel(const int* __restrict__ deg,
                                                       float* __restrict__ asum, int N) {
    int n = blockIdx.x * 256 + threadIdx.x;
    if (n >= N) return;
    float inv = 1.0f / (float)max(deg[n], 1);
    asum[n * 3 + 0] *= inv;
    asum[n * 3 + 1] *= inv;
    asum[n * 3 + 2] *= inv;
}

// exclusive scan of (deg[n]+1), single block of 1024 threads
__global__ __launch_bounds__(1024) void scan_kernel(const int* __restrict__ deg,
                                                    int* __restrict__ rowptr, int N) {
    __shared__ int wsum[16];
    __shared__ int carry_s;
    int tid = threadIdx.x, lane = tid & 63, wid = tid >> 6;
    if (tid == 0) carry_s = 0;
    __syncthreads();
    for (int base = 0; base < N; base += 1024) {
        int idx = base + tid;
        int v = (idx < N) ? deg[idx] + 1 : 0;
        int x = v;
        #pragma unroll
        for (int off = 1; off < 64; off <<= 1) {
            int t = __shfl_up(x, off);
            if (lane >= off) x += t;
        }
        if (lane == 63) wsum[wid] = x;
        __syncthreads();
        if (wid == 0) {
            int y = (lane < 16) ? wsum[lane] : 0;
            #pragma unroll
            for (int off = 1; off < 16; off <<= 1) {
                int t = __shfl_up(y, off);
                if (lane >= off) y += t;
            }
            if (lane < 16) wsum[lane] = y;
        }
        __syncthreads();
        int woff = (wid > 0) ? wsum[wid - 1] : 0;
        int incl = carry_s + woff + x;
        if (idx < N) rowptr[idx] = incl - v;  // exclusive
        __syncthreads();
        if (tid == 1023) carry_s += wsum[15];
        __syncthreads();
    }
    if (threadIdx.x == 0) rowptr[N] = carry_s;
}

__global__ __launch_bounds__(256) void copy_kernel(const int* __restrict__ a,
                                                   int* __restrict__ b, int N) {
    int n = blockIdx.x * 256 + threadIdx.x;
    if (n < N) b[n] = a[n];
}

__global__ __launch_bounds__(256) void fill_kernel(const int* __restrict__ ei,
                                                   int* __restrict__ cursor,
                                                   int* __restrict__ csr_src,
                                                   int* __restrict__ csr_eid,
                                                   int E, int E2) {
    int e = blockIdx.x * 256 + threadIdx.x;
    if (e >= E2) return;
    int src, dst;
    if (e < E) { src = ei[e]; dst = ei[E + e]; }
    else       { src = e - E; dst = e - E; }
    int pos = atomicAdd(&cursor[dst], 1);
    csr_src[pos] = src;
    csr_eid[pos] = e;
}

// ---------------------------------------------------------------- GEMM (fp32)
// Y[N,M] = A[N,K] @ W[K,M] + bias ; 128x128 tile, BK=8, 256 thr, 8x8/thread

__global__ __launch_bounds__(256) void gemm_bias(const float* __restrict__ A,
                                                 const float* __restrict__ W,
                                                 const float* __restrict__ bias,
                                                 float* __restrict__ Y,
                                                 int N, int K, int M) {
    __shared__ float As[8][132];
    __shared__ float Ws[8][132];
    int tid = threadIdx.x;
    int bm = blockIdx.x * 128, bn = blockIdx.y * 128;
    int tx = tid & 15, ty = tid >> 4;
    float acc[8][8] = {};
    int a_m = tid >> 1, a_k = (tid & 1) * 4;
    int w_k = tid >> 5, w_n = (tid & 31) * 4;
    for (int k0 = 0; k0 < K; k0 += 8) {
        int row = bm + a_m;
        float4 av = make_float4(0.f, 0.f, 0.f, 0.f);
        if (row < N) av = *reinterpret_cast<const float4*>(A + (size_t)row * K + k0 + a_k);
        As[a_k + 0][a_m] = av.x; As[a_k + 1][a_m] = av.y;
        As[a_k + 2][a_m] = av.z; As[a_k + 3][a_m] = av.w;
        float4 wv = *reinterpret_cast<const float4*>(W + (size_t)(k0 + w_k) * M + bn + w_n);
        *reinterpret_cast<float4*>(&Ws[w_k][w_n]) = wv;
        __syncthreads();
        #pragma unroll
        for (int k = 0; k < 8; k++) {
            float4 a0 = *reinterpret_cast<float4*>(&As[k][ty * 8]);
            float4 a1 = *reinterpret_cast<float4*>(&As[k][ty * 8 + 4]);
            float4 w0 = *reinterpret_cast<float4*>(&Ws[k][tx * 8]);
            float4 w1 = *reinterpret_cast<float4*>(&Ws[k][tx * 8 + 4]);
            float a[8] = {a0.x, a0.y, a0.z, a0.w, a1.x, a1.y, a1.z, a1.w};
            float b[8] = {w0.x, w0.y, w0.z, w0.w, w1.x, w1.y, w1.z, w1.w};
            #pragma unroll
            for (int i = 0; i < 8; i++)
                #pragma unroll
                for (int j = 0; j < 8; j++) acc[i][j] += a[i] * b[j];
        }
        __syncthreads();
    }
    #pragma unroll
    for (int i = 0; i < 8; i++) {
        int row = bm + ty * 8 + i;
        if (row < N) {
            #pragma unroll
            for (int j = 0; j < 8; j++) {
                int col = bn + tx * 8 + j;
                Y[(size_t)row * M + col] = acc[i][j] + bias[col];
            }
        }
    }
}

// ---------------------------------------------------------------- fused GATv2
// One block per dst node: for each chunk of incoming edges, gather (or, for
// layer 1, recompute) xl[src] rows into LDS ONCE, compute attention logits
// (wave per edge, lanes over channels), merge into an online softmax, and
// accumulate the weighted sum — single pass over edges, xr gathered once.

template <int HC, bool L1>
__global__ __launch_bounds__(256) void attn_fused(
    const int* __restrict__ rowptr, const int* __restrict__ csr_src,
    const int* __restrict__ csr_eid, const float* __restrict__ eattr,
    const float* __restrict__ lattr, const float* __restrict__ x8,
    const float* __restrict__ Wl, const float* __restrict__ bl,
    const float* __restrict__ Wr, const float* __restrict__ br,
    const float* __restrict__ XL, const float* __restrict__ XR,
    const float* __restrict__ We, const float* __restrict__ att,
    const float* __restrict__ bo, float* __restrict__ out, int E) {
    constexpr int H = HC / 128;
    constexpr int CH = (HC == 512) ? 8 : 16;   // edges per chunk
    constexpr int PT = (HC + 255) / 256;       // channels per thread

    __shared__ float s_xr[HC];
    __shared__ float s_xl[CH][HC];
    __shared__ float s_ea[CH][3];
    __shared__ float s_logit[CH][H];
    __shared__ float s_w[CH][H];
    __shared__ float s_scale[H];
    __shared__ float s_m[H], s_l[H];
    __shared__ int   s_src[CH];
    __shared__ float s_x8s[L1 ? CH * 8 : 1];
    __shared__ float s_xn8[L1 ? 8 : 1];

    int n = blockIdx.x;
    int tid = threadIdx.x;
    int beg = rowptr[n], end = rowptr[n + 1];

    // xr[dst]: once per node
    if (L1) {
        if (tid < 8) s_xn8[tid] = x8[(size_t)n * 8 + tid];
        __syncthreads();
        for (int c = tid; c < HC; c += 256) {
            float v = br[c];
            #pragma unroll
            for (int kk = 0; kk < 8; kk++) v += s_xn8[kk] * Wr[kk * HC + c];
            s_xr[c] = v;
        }
    } else {
        for (int c = tid; c < HC; c += 256) s_xr[c] = XR[(size_t)n * HC + c];
    }
    if (tid < H) { s_m[tid] = -INFINITY; s_l[tid] = 0.f; }
    float acc[PT];
    #pragma unroll
    for (int p = 0; p < PT; p++) acc[p] = 0.f;
    __syncthreads();

    for (int jb = beg; jb < end; jb += CH) {
        int nc = min(CH, end - jb);
        // edge metadata
        if (tid < nc) {
            s_src[tid] = csr_src[jb + tid];
            int eid = csr_eid[jb + tid];
            const float* ea = (eid < E) ? (eattr + (size_t)eid * 3)
                                        : (lattr + (size_t)n * 3);
            s_ea[tid][0] = ea[0]; s_ea[tid][1] = ea[1]; s_ea[tid][2] = ea[2];
        }
        __syncthreads();
        // xl rows into LDS (once per edge)
        if (L1) {
            if (tid < nc * 8)
                s_x8s[tid] = x8[(size_t)s_src[tid >> 3] * 8 + (tid & 7)];
            __syncthreads();
            for (int i = tid; i < nc * HC; i += 256) {
                int j = i >> 9, c = i & (HC - 1);   // HC==512 here
                float v = bl[c];
                #pragma unroll
                for (int kk = 0; kk < 8; kk++) v += s_x8s[j * 8 + kk] * Wl[kk * HC + c];
                s_xl[j][c] = v;
            }
        } else {
            constexpr int Q = HC / 4;
            for (int i = tid; i < nc * Q; i += 256) {
                int j = i / Q, c4 = i - j * Q;
                reinterpret_cast<float4*>(s_xl[j])[c4] =
                    reinterpret_cast<const float4*>(XL + (size_t)s_src[j] * HC)[c4];
            }
        }
        __syncthreads();
        // logits: one wave per edge, lanes over channels
        {
            int wid = tid >> 6, lane = tid & 63;
            for (int j = wid; j < nc; j += 4) {
                float hs[H];
                #pragma unroll
                for (int h = 0; h < H; h++) hs[h] = 0.f;
                #pragma unroll
                for (int k = 0; k < HC / 64; k++) {
                    int c = k * 64 + lane;
                    float ee = s_ea[j][0] * We[c] + s_ea[j][1] * We[HC + c] +
                               s_ea[j][2] * We[2 * HC + c];
                    float u = s_xl[j][c] + s_xr[c] + ee;
                    float lr = u > 0.f ? u : 0.2f * u;
                    hs[k >> 1] += lr * att[c];
                }
                #pragma unroll
                for (int h = 0; h < H; h++) {
                    float v = hs[h];
                    #pragma unroll
                    for (int off = 32; off; off >>= 1) v += __shfl_xor(v, off);
                    if (lane == 0) s_logit[j][h] = v;
                }
            }
        }
        __syncthreads();
        // online softmax bookkeeping (thread h per head)
        if (tid < H) {
            float mo = s_m[tid], mn = mo;
            for (int j = 0; j < nc; j++) mn = fmaxf(mn, s_logit[j][tid]);
            float sc = expf(mo - mn);        // exp(-inf)=0 on first chunk
            float l = s_l[tid] * sc;
            for (int j = 0; j < nc; j++) {
                float w = expf(s_logit[j][tid] - mn);
                s_w[j][tid] = w;
                l += w;
            }
            s_m[tid] = mn; s_l[tid] = l; s_scale[tid] = sc;
        }
        __syncthreads();
        // accumulate weighted xl
        #pragma unroll
        for (int p = 0; p < PT; p++) {
            int c = tid + p * 256;
            if (c < HC) {
                int h = c >> 7;
                float a = acc[p] * s_scale[h];
                for (int j = 0; j < nc; j++) a += s_w[j][h] * s_xl[j][c];
                acc[p] = a;
            }
        }
        __syncthreads();
    }
    #pragma unroll
    for (int p = 0; p < PT; p++) {
        int c = tid + p * 256;
        if (c < HC)
            out[(size_t)n * HC + c] = acc[p] / (s_l[c >> 7] + 1e-16f) + bo[c];
    }
}

// ---------------------------------------------------------------- layernorm

__global__ __launch_bounds__(256) void ln_stats(const float* __restrict__ x,
                                                double* __restrict__ stats, size_t count) {
    double s = 0.0, s2 = 0.0;
    for (size_t i = (size_t)blockIdx.x * 256 + threadIdx.x; i < count;
         i += (size_t)gridDim.x * 256) {
        double v = (double)x[i];
        s += v; s2 += v * v;
    }
    #pragma unroll
    for (int off = 32; off; off >>= 1) {
        s += __shfl_xor(s, off);
        s2 += __shfl_xor(s2, off);
    }
    __shared__ double wsh[4], wsh2[4];
    int wid = threadIdx.x >> 6, lane = threadIdx.x & 63;
    if (lane == 0) { wsh[wid] = s; wsh2[wid] = s2; }
    __syncthreads();
    if (threadIdx.x == 0) {
        double a = 0.0, b = 0.0;
        for (int w = 0; w < 4; w++) { a += wsh[w]; b += wsh2[w]; }
        atomicAdd(&stats[0], a);
        atomicAdd(&stats[1], b);
    }
}

__global__ __launch_bounds__(256) void ln_apply_elu(float* __restrict__ x,
                                                    const double* __restrict__ stats,
                                                    const float* __restrict__ w,
                                                    const float* __restrict__ b,
                                                    int F, size_t count) {
    double mu = stats[0] / (double)count;
    double var = stats[1] / (double)count - mu * mu;
    float sd = (float)sqrt(var > 0.0 ? var : 0.0);
    float rs = 1.f / (sd + 1e-5f);
    float muf = (float)mu;
    for (size_t i = (size_t)blockIdx.x * 256 + threadIdx.x; i < count;
         i += (size_t)gridDim.x * 256) {
        int c = (int)(i & (size_t)(F - 1));
        float v = (x[i] - muf) * rs * w[c] + b[c];
        x[i] = v > 0.f ? v : expm1f(v);
    }
}

// ---------------------------------------------------------------- pooling

__global__ __launch_bounds__(256) void gcnt_kernel(const int* __restrict__ batch,
                                                   int* __restrict__ gcnt, int N) {
    int n = blockIdx.x * 256 + threadIdx.x;
    if (n < N) atomicAdd(&gcnt[batch[n]], 1);
}

// inclusive scan of the 64 graph counts -> offsets (one wave)
__global__ __launch_bounds__(64) void gscan_kernel(const int* __restrict__ gcnt,
                                                   int* __restrict__ goff) {
    int t = threadIdx.x;
    int x = gcnt[t];
    #pragma unroll
    for (int off = 1; off < 64; off <<= 1) {
        int v = __shfl_up(x, off);
        if (t >= off) x += v;
    }
    goff[t + 1] = x;
    if (t == 0) goff[0] = 0;
}

// one block per graph: mean+max over its node range (batch is sorted)
__global__ __launch_bounds__(256) void pool_kernel(const float* __restrict__ h,
                                                   const int* __restrict__ goff,
                                                   float* __restrict__ out) {
    __shared__ float sh[128], mh[128];
    int g = blockIdx.x;
    int s = goff[g], e = goff[g + 1];
    int tid = threadIdx.x;
    int c = tid & 127, part = tid >> 7;
    float sum = 0.f, mx = -INFINITY;
    for (int n = s + part; n < e; n += 2) {
        float v = h[(size_t)n * 128 + c];
        sum += v;
        mx = fmaxf(mx, v);
    }
    if (part == 1) { sh[c] = sum; mh[c] = mx; }
    __syncthreads();
    if (part == 0) {
        if (e - s > 1) { sum += sh[c]; mx = fmaxf(mx, mh[c]); }
        int cnt = e - s;
        out[g * 256 + c] = cnt > 0 ? sum / (float)cnt : 0.f;
        out[g * 256 + 128 + c] = cnt > 0 ? mx : 0.f;
    }
}

// ---------------------------------------------------------------- launch

extern "C" void kernel_launch(void* const* d_in, const int* in_sizes, int n_in,
                              void* d_out, int out_size, void* d_ws, size_t ws_size,
                              hipStream_t stream) {
    const int N = N_NODES, E = N_EDGES, G = N_GRAPHS, E2 = E2_TOTAL;
    const float* x = (const float*)d_in[0];
    const int* ei = (const int*)d_in[1];
    const float* eattr = (const float*)d_in[2];
    const int* batch = (const int*)d_in[3];
    auto P = [&](int l, int k) { return (const float*)d_in[4 + l * 9 + k]; };
    // k: 0=Wl 1=bl 2=Wr 3=br 4=We 5=att 6=bo 7=lnw 8=lnb

    char* w = (char*)d_ws;
    size_t off = 0;
    auto alloc = [&](size_t bytes) -> void* {
        void* p = w + off;
        off += (bytes + 255) & ~(size_t)255;
        return p;
    };
    float* B0 = (float*)alloc((size_t)N * 512 * 4);  // H1 -> H2 -> (tail) H3
    float* B1 = (float*)alloc((size_t)N * 256 * 4);  // XL2 -> XL3
    float* B2 = (float*)alloc((size_t)N * 256 * 4);  // XR2 -> XR3
    int* csr_src = (int*)alloc((size_t)E2 * 4);
    int* csr_eid = (int*)alloc((size_t)E2 * 4);
    int* rowptr = (int*)alloc((size_t)(N + 1) * 4);
    int* cursor = (int*)alloc((size_t)N * 4);
    int* deg = (int*)alloc((size_t)N * 4);
    float* lattr = (float*)alloc((size_t)N * 3 * 4);
    double* stats = (double*)alloc(6 * 8);
    int* gcnt = (int*)alloc((size_t)G * 4);
    int* goff = (int*)alloc((size_t)(G + 1) * 4);
    float* H3 = B0 + (size_t)N * 256;                // tail half of B0
    (void)ws_size; (void)n_in; (void)in_sizes; (void)out_size;

    hipMemsetAsync(deg, 0, (size_t)N * 4, stream);
    hipMemsetAsync(lattr, 0, (size_t)N * 3 * 4, stream);
    hipMemsetAsync(stats, 0, 6 * 8, stream);
    hipMemsetAsync(gcnt, 0, (size_t)G * 4, stream);

    deg_kernel<<<(E + 255) / 256, 256, 0, stream>>>(ei, eattr, deg, lattr, E);
    loopattr_kernel<<<(N + 255) / 256, 256, 0, stream>>>(deg, lattr, N);
    scan_kernel<<<1, 1024, 0, stream>>>(deg, rowptr, N);
    copy_kernel<<<(N + 255) / 256, 256, 0, stream>>>(rowptr, cursor, N);
    fill_kernel<<<(E2 + 255) / 256, 256, 0, stream>>>(ei, cursor, csr_src, csr_eid, E, E2);
    gcnt_kernel<<<(N + 255) / 256, 256, 0, stream>>>(batch, gcnt, N);
    gscan_kernel<<<1, 64, 0, stream>>>(gcnt, goff);

    // -------- layer 1 (din=8, H=4, HC=512): xl/xr recomputed from x
    attn_fused<512, true><<<N, 256, 0, stream>>>(
        rowptr, csr_src, csr_eid, eattr, lattr, x,
        P(0, 0), P(0, 1), P(0, 2), P(0, 3), nullptr, nullptr,
        P(0, 4), P(0, 5), P(0, 6), B0, E);
    ln_stats<<<2048, 256, 0, stream>>>(B0, stats + 0, (size_t)N * 512);
    ln_apply_elu<<<2048, 256, 0, stream>>>(B0, stats + 0, P(0, 7), P(0, 8), 512,
                                           (size_t)N * 512);

    // -------- layer 2 (din=512, H=2, HC=256)
    {
        dim3 g((N + 127) / 128, 2);
        gemm_bias<<<g, 256, 0, stream>>>(B0, P(1, 0), P(1, 1), B1, N, 512, 256);
        gemm_bias<<<g, 256, 0, stream>>>(B0, P(1, 2), P(1, 3), B2, N, 512, 256);
    }
    attn_fused<256, false><<<N, 256, 0, stream>>>(
        rowptr, csr_src, csr_eid, eattr, lattr, nullptr,
        nullptr, nullptr, nullptr, nullptr, B1, B2,
        P(1, 4), P(1, 5), P(1, 6), B0, E);   // H2 -> front of B0
    ln_stats<<<2048, 256, 0, stream>>>(B0, stats + 2, (size_t)N * 256);
    ln_apply_elu<<<2048, 256, 0, stream>>>(B0, stats + 2, P(1, 7), P(1, 8), 256,
                                           (size_t)N * 256);

    // -------- layer 3 (din=256, H=1, HC=128)
    {
        dim3 g((N + 127) / 128, 1);
        gemm_bias<<<g, 256, 0, stream>>>(B0, P(2, 0), P(2, 1), B1, N, 256, 128);
        gemm_bias<<<g, 256, 0, stream>>>(B0, P(2, 2), P(2, 3), B2, N, 256, 128);
    }
    attn_fused<128, false><<<N, 256, 0, stream>>>(
        rowptr, csr_src, csr_eid, eattr, lattr, nullptr,
        nullptr, nullptr, nullptr, nullptr, B1, B2,
        P(2, 4), P(2, 5), P(2, 6), H3, E);
    ln_stats<<<2048, 256, 0, stream>>>(H3, stats + 4, (size_t)N * 128);
    ln_apply_elu<<<2048, 256, 0, stream>>>(H3, stats + 4, P(2, 7), P(2, 8), 128,
                                           (size_t)N * 128);

    // -------- pooling (zero atomics)
    pool_kernel<<<G, 256, 0, stream>>>(H3, goff, (float*)d_out);
}

// Round 3
// 2486.757 us; speedup vs baseline: 1.4975x; 1.2081x over previous
//
#include <hip/hip_runtime.h>
#include <hip/hip_bf16.h>
#include <math.h>

#define N_NODES 50000
#define N_EDGES 800000
#define N_GRAPHS 64
#define E2_TOTAL (N_EDGES + N_NODES)

typedef unsigned short u16;

__device__ __forceinline__ u16 f2bf(float f) {
    unsigned u = __float_as_uint(f);
    u += 0x7fffu + ((u >> 16) & 1u);   // round-to-nearest-even
    return (u16)(u >> 16);
}
__device__ __forceinline__ float bf2f(u16 s) {
    return __uint_as_float((unsigned)s << 16);
}

// ---------------------------------------------------------------- CSR build

__global__ __launch_bounds__(256) void deg_kernel(const int* __restrict__ ei,
                                                  const float* __restrict__ eattr,
                                                  int* __restrict__ deg,
                                                  float* __restrict__ asum, int E) {
    int e = blockIdx.x * 256 + threadIdx.x;
    if (e >= E) return;
    int dst = ei[E + e];
    atomicAdd(&deg[dst], 1);
    atomicAdd(&asum[dst * 3 + 0], eattr[e * 3 + 0]);
    atomicAdd(&asum[dst * 3 + 1], eattr[e * 3 + 1]);
    atomicAdd(&asum[dst * 3 + 2], eattr[e * 3 + 2]);
}

__global__ __launch_bounds__(256) void loopattr_kernel(const int* __restrict__ deg,
                                                       float* __restrict__ asum, int N) {
    int n = blockIdx.x * 256 + threadIdx.x;
    if (n >= N) return;
    float inv = 1.0f / (float)max(deg[n], 1);
    asum[n * 3 + 0] *= inv;
    asum[n * 3 + 1] *= inv;
    asum[n * 3 + 2] *= inv;
}

__global__ __launch_bounds__(1024) void scan_kernel(const int* __restrict__ deg,
                                                    int* __restrict__ rowptr, int N) {
    __shared__ int wsum[16];
    __shared__ int carry_s;
    int tid = threadIdx.x, lane = tid & 63, wid = tid >> 6;
    if (tid == 0) carry_s = 0;
    __syncthreads();
    for (int base = 0; base < N; base += 1024) {
        int idx = base + tid;
        int v = (idx < N) ? deg[idx] + 1 : 0;
        int x = v;
        #pragma unroll
        for (int off = 1; off < 64; off <<= 1) {
            int t = __shfl_up(x, off);
            if (lane >= off) x += t;
        }
        if (lane == 63) wsum[wid] = x;
        __syncthreads();
        if (wid == 0) {
            int y = (lane < 16) ? wsum[lane] : 0;
            #pragma unroll
            for (int off = 1; off < 16; off <<= 1) {
                int t = __shfl_up(y, off);
                if (lane >= off) y += t;
            }
            if (lane < 16) wsum[lane] = y;
        }
        __syncthreads();
        int woff = (wid > 0) ? wsum[wid - 1] : 0;
        int incl = carry_s + woff + x;
        if (idx < N) rowptr[idx] = incl - v;  // exclusive
        __syncthreads();
        if (tid == 1023) carry_s += wsum[15];
        __syncthreads();
    }
    if (threadIdx.x == 0) rowptr[N] = carry_s;
}

__global__ __launch_bounds__(256) void copy_kernel(const int* __restrict__ a,
                                                   int* __restrict__ b, int N) {
    int n = blockIdx.x * 256 + threadIdx.x;
    if (n < N) b[n] = a[n];
}

__global__ __launch_bounds__(256) void fill_kernel(const int* __restrict__ ei,
                                                   int* __restrict__ cursor,
                                                   int* __restrict__ csr_src,
                                                   int* __restrict__ csr_eid,
                                                   int E, int E2) {
    int e = blockIdx.x * 256 + threadIdx.x;
    if (e >= E2) return;
    int src, dst;
    if (e < E) { src = ei[e]; dst = ei[E + e]; }
    else       { src = e - E; dst = e - E; }
    int pos = atomicAdd(&cursor[dst], 1);
    csr_src[pos] = src;
    csr_eid[pos] = e;
}

// ---------------------------------------------------------------- XL1 = x@Wl1+bl1 (din=8) -> bf16

__global__ __launch_bounds__(256) void xw8_kernel(const float* __restrict__ x,
                                                  const float* __restrict__ Wl,
                                                  const float* __restrict__ bl,
                                                  u16* __restrict__ XLbf, int N) {
    __shared__ float sW[8 * 512];
    __shared__ float sb[512];
    __shared__ float sx[64][8];
    int tid = threadIdx.x;
    int nb = blockIdx.x * 64;
    for (int i = tid; i < 8 * 512; i += 256) sW[i] = Wl[i];
    for (int i = tid; i < 512; i += 256) sb[i] = bl[i];
    for (int i = tid; i < 64 * 8; i += 256) {
        int j = i >> 3, k = i & 7;
        int n = nb + j;
        sx[j][k] = (n < N) ? x[(size_t)n * 8 + k] : 0.f;
    }
    __syncthreads();
    // each iter: one node j, channel pair c2
    for (int it = 0; it < 64; it++) {
        int i = tid + it * 256;
        int j = i >> 8, c2 = (i & 255) * 2;
        int n = nb + j;
        if (n < N) {
            float v0 = sb[c2], v1 = sb[c2 + 1];
            #pragma unroll
            for (int k = 0; k < 8; k++) {
                v0 += sx[j][k] * sW[k * 512 + c2];
                v1 += sx[j][k] * sW[k * 512 + c2 + 1];
            }
            ushort2 o; o.x = f2bf(v0); o.y = f2bf(v1);
            *reinterpret_cast<ushort2*>(XLbf + (size_t)n * 512 + c2) = o;
        }
    }
}

// ---------------------------------------------------------------- GEMM (fp32 in, fp32/bf16 out)
// Y[N,M] = A[N,K] @ W[K,M] + bias ; 128x128 tile, BK=8, 256 thr, 8x8/thread

template <bool BF16OUT>
__global__ __launch_bounds__(256) void gemm_bias(const float* __restrict__ A,
                                                 const float* __restrict__ W,
                                                 const float* __restrict__ bias,
                                                 float* __restrict__ Yf,
                                                 u16* __restrict__ Yb,
                                                 int N, int K, int M) {
    __shared__ float As[8][132];
    __shared__ float Ws[8][132];
    int tid = threadIdx.x;
    int bm = blockIdx.x * 128, bn = blockIdx.y * 128;
    int tx = tid & 15, ty = tid >> 4;
    float acc[8][8] = {};
    int a_m = tid >> 1, a_k = (tid & 1) * 4;
    int w_k = tid >> 5, w_n = (tid & 31) * 4;
    for (int k0 = 0; k0 < K; k0 += 8) {
        int row = bm + a_m;
        float4 av = make_float4(0.f, 0.f, 0.f, 0.f);
        if (row < N) av = *reinterpret_cast<const float4*>(A + (size_t)row * K + k0 + a_k);
        As[a_k + 0][a_m] = av.x; As[a_k + 1][a_m] = av.y;
        As[a_k + 2][a_m] = av.z; As[a_k + 3][a_m] = av.w;
        float4 wv = *reinterpret_cast<const float4*>(W + (size_t)(k0 + w_k) * M + bn + w_n);
        *reinterpret_cast<float4*>(&Ws[w_k][w_n]) = wv;
        __syncthreads();
        #pragma unroll
        for (int k = 0; k < 8; k++) {
            float4 a0 = *reinterpret_cast<float4*>(&As[k][ty * 8]);
            float4 a1 = *reinterpret_cast<float4*>(&As[k][ty * 8 + 4]);
            float4 w0 = *reinterpret_cast<float4*>(&Ws[k][tx * 8]);
            float4 w1 = *reinterpret_cast<float4*>(&Ws[k][tx * 8 + 4]);
            float a[8] = {a0.x, a0.y, a0.z, a0.w, a1.x, a1.y, a1.z, a1.w};
            float b[8] = {w0.x, w0.y, w0.z, w0.w, w1.x, w1.y, w1.z, w1.w};
            #pragma unroll
            for (int i = 0; i < 8; i++)
                #pragma unroll
                for (int j = 0; j < 8; j++) acc[i][j] += a[i] * b[j];
        }
        __syncthreads();
    }
    #pragma unroll
    for (int i = 0; i < 8; i++) {
        int row = bm + ty * 8 + i;
        if (row < N) {
            if (BF16OUT) {
                u16 tmp[8];
                #pragma unroll
                for (int j = 0; j < 8; j++) tmp[j] = f2bf(acc[i][j] + bias[bn + tx * 8 + j]);
                *reinterpret_cast<uint4*>(Yb + (size_t)row * M + bn + tx * 8) =
                    *reinterpret_cast<uint4*>(tmp);
            } else {
                #pragma unroll
                for (int j = 0; j < 8; j++) {
                    int col = bn + tx * 8 + j;
                    Yf[(size_t)row * M + col] = acc[i][j] + bias[col];
                }
            }
        }
    }
}

// ---------------------------------------------------------------- fused GATv2
// One block per dst node. XL gathered as bf16; xr: recomputed from x (L1) or
// loaded fp32 (L2/3). Online softmax, single pass over incoming edges.

template <int HC, bool L1>
__global__ __launch_bounds__(256) void attn_fused(
    const int* __restrict__ rowptr, const int* __restrict__ csr_src,
    const int* __restrict__ csr_eid, const float* __restrict__ eattr,
    const float* __restrict__ lattr, const float* __restrict__ x8,
    const float* __restrict__ Wr, const float* __restrict__ br,
    const u16* __restrict__ XLbf, const float* __restrict__ XR,
    const float* __restrict__ We, const float* __restrict__ att,
    const float* __restrict__ bo, float* __restrict__ out, int E) {
    constexpr int H = HC / 128;
    constexpr int CH = (HC == 512) ? 16 : 32;  // edges per chunk
    constexpr int PT = (HC + 255) / 256;       // channels per thread
    constexpr int V = HC / 8;                  // uint4 (8 bf16) per row

    __shared__ float s_xr[HC];
    __shared__ __align__(16) u16 s_xl[CH][HC];
    __shared__ float s_We[3 * HC];
    __shared__ float s_att[HC];
    __shared__ float s_ea[CH][3];
    __shared__ float s_logit[CH][H];
    __shared__ float s_w[CH][H];
    __shared__ float s_scale[H];
    __shared__ float s_m[H], s_l[H];
    __shared__ int   s_src[CH];
    __shared__ float s_xn8[L1 ? 8 : 1];

    int n = blockIdx.x;
    int tid = threadIdx.x;
    int beg = rowptr[n], end = rowptr[n + 1];

    for (int i = tid; i < 3 * HC; i += 256) s_We[i] = We[i];
    for (int i = tid; i < HC; i += 256) s_att[i] = att[i];
    if (L1) {
        if (tid < 8) s_xn8[tid] = x8[(size_t)n * 8 + tid];
        __syncthreads();
        for (int c = tid; c < HC; c += 256) {
            float v = br[c];
            #pragma unroll
            for (int kk = 0; kk < 8; kk++) v += s_xn8[kk] * Wr[kk * HC + c];
            s_xr[c] = v;
        }
    } else {
        for (int c = tid; c < HC; c += 256) s_xr[c] = XR[(size_t)n * HC + c];
    }
    if (tid < H) { s_m[tid] = -INFINITY; s_l[tid] = 0.f; }
    float acc[PT];
    #pragma unroll
    for (int p = 0; p < PT; p++) acc[p] = 0.f;
    __syncthreads();

    for (int jb = beg; jb < end; jb += CH) {
        int nc = min(CH, end - jb);
        if (tid < nc) {
            s_src[tid] = csr_src[jb + tid];
            int eid = csr_eid[jb + tid];
            const float* ea = (eid < E) ? (eattr + (size_t)eid * 3)
                                        : (lattr + (size_t)n * 3);
            s_ea[tid][0] = ea[0]; s_ea[tid][1] = ea[1]; s_ea[tid][2] = ea[2];
        }
        __syncthreads();
        // gather bf16 xl rows (16B vector loads)
        for (int i = tid; i < nc * V; i += 256) {
            int j = i / V, q = i - j * V;
            reinterpret_cast<uint4*>(&s_xl[j][0])[q] =
                reinterpret_cast<const uint4*>(XLbf + (size_t)s_src[j] * HC)[q];
        }
        __syncthreads();
        // logits: one wave per edge
        {
            int wid = tid >> 6, lane = tid & 63;
            for (int j = wid; j < nc; j += 4) {
                float ea0 = s_ea[j][0], ea1 = s_ea[j][1], ea2 = s_ea[j][2];
                float hs[H];
                #pragma unroll
                for (int h = 0; h < H; h++) hs[h] = 0.f;
                #pragma unroll
                for (int k = 0; k < HC / 64; k++) {
                    int c = k * 64 + lane;
                    float ee = ea0 * s_We[c] + ea1 * s_We[HC + c] + ea2 * s_We[2 * HC + c];
                    float u = bf2f(s_xl[j][c]) + s_xr[c] + ee;
                    float lr = u > 0.f ? u : 0.2f * u;
                    hs[k >> 1] += lr * s_att[c];
                }
                #pragma unroll
                for (int h = 0; h < H; h++) {
                    float v = hs[h];
                    #pragma unroll
                    for (int off = 32; off; off >>= 1) v += __shfl_xor(v, off);
                    if (lane == 0) s_logit[j][h] = v;
                }
            }
        }
        __syncthreads();
        // online softmax: wave h per head, lane per edge
        {
            int wid = tid >> 6, lane = tid & 63;
            if (wid < H) {
                int h = wid;
                float cur = (lane < nc) ? s_logit[lane][h] : -INFINITY;
                float cm = cur;
                #pragma unroll
                for (int off = 32; off; off >>= 1) cm = fmaxf(cm, __shfl_xor(cm, off));
                float mo = s_m[h];
                float mn = fmaxf(mo, cm);
                float sc = __expf(mo - mn);            // 0 on first chunk
                float w = (lane < nc) ? __expf(cur - mn) : 0.f;
                if (lane < nc) s_w[lane][h] = w;
                float ws = w;
                #pragma unroll
                for (int off = 32; off; off >>= 1) ws += __shfl_xor(ws, off);
                if (lane == 0) {
                    s_m[h] = mn;
                    s_l[h] = s_l[h] * sc + ws;
                    s_scale[h] = sc;
                }
            }
        }
        __syncthreads();
        // accumulate weighted xl
        #pragma unroll
        for (int p = 0; p < PT; p++) {
            int c = tid + p * 256;
            if (c < HC) {
                int h = c >> 7;
                float a = acc[p] * s_scale[h];
                for (int j = 0; j < nc; j++) a += s_w[j][h] * bf2f(s_xl[j][c]);
                acc[p] = a;
            }
        }
        __syncthreads();
    }
    #pragma unroll
    for (int p = 0; p < PT; p++) {
        int c = tid + p * 256;
        if (c < HC)
            out[(size_t)n * HC + c] = acc[p] / (s_l[c >> 7] + 1e-16f) + bo[c];
    }
}

// ---------------------------------------------------------------- layernorm

__global__ __launch_bounds__(256) void ln_stats(const float* __restrict__ x,
                                                double* __restrict__ stats, size_t count) {
    double s = 0.0, s2 = 0.0;
    for (size_t i = (size_t)blockIdx.x * 256 + threadIdx.x; i < count;
         i += (size_t)gridDim.x * 256) {
        double v = (double)x[i];
        s += v; s2 += v * v;
    }
    #pragma unroll
    for (int off = 32; off; off >>= 1) {
        s += __shfl_xor(s, off);
        s2 += __shfl_xor(s2, off);
    }
    __shared__ double wsh[4], wsh2[4];
    int wid = threadIdx.x >> 6, lane = threadIdx.x & 63;
    if (lane == 0) { wsh[wid] = s; wsh2[wid] = s2; }
    __syncthreads();
    if (threadIdx.x == 0) {
        double a = 0.0, b = 0.0;
        for (int w = 0; w < 4; w++) { a += wsh[w]; b += wsh2[w]; }
        atomicAdd(&stats[0], a);
        atomicAdd(&stats[1], b);
    }
}

__global__ __launch_bounds__(256) void ln_apply_elu(float* __restrict__ x,
                                                    const double* __restrict__ stats,
                                                    const float* __restrict__ w,
                                                    const float* __restrict__ b,
                                                    int F, size_t count) {
    double mu = stats[0] / (double)count;
    double var = stats[1] / (double)count - mu * mu;
    float sd = (float)sqrt(var > 0.0 ? var : 0.0);
    float rs = 1.f / (sd + 1e-5f);
    float muf = (float)mu;
    for (size_t i = (size_t)blockIdx.x * 256 + threadIdx.x; i < count;
         i += (size_t)gridDim.x * 256) {
        int c = (int)(i & (size_t)(F - 1));
        float v = (x[i] - muf) * rs * w[c] + b[c];
        x[i] = v > 0.f ? v : expm1f(v);
    }
}

// ---------------------------------------------------------------- pooling

__global__ __launch_bounds__(256) void gcnt_kernel(const int* __restrict__ batch,
                                                   int* __restrict__ gcnt, int N) {
    int n = blockIdx.x * 256 + threadIdx.x;
    if (n < N) atomicAdd(&gcnt[batch[n]], 1);
}

__global__ __launch_bounds__(64) void gscan_kernel(const int* __restrict__ gcnt,
                                                   int* __restrict__ goff) {
    int t = threadIdx.x;
    int x = gcnt[t];
    #pragma unroll
    for (int off = 1; off < 64; off <<= 1) {
        int v = __shfl_up(x, off);
        if (t >= off) x += v;
    }
    goff[t + 1] = x;
    if (t == 0) goff[0] = 0;
}

__global__ __launch_bounds__(256) void pool_kernel(const float* __restrict__ h,
                                                   const int* __restrict__ goff,
                                                   float* __restrict__ out) {
    __shared__ float sh[128], mh[128];
    int g = blockIdx.x;
    int s = goff[g], e = goff[g + 1];
    int tid = threadIdx.x;
    int c = tid & 127, part = tid >> 7;
    float sum = 0.f, mx = -INFINITY;
    for (int n = s + part; n < e; n += 2) {
        float v = h[(size_t)n * 128 + c];
        sum += v;
        mx = fmaxf(mx, v);
    }
    if (part == 1) { sh[c] = sum; mh[c] = mx; }
    __syncthreads();
    if (part == 0) {
        if (e - s > 1) { sum += sh[c]; mx = fmaxf(mx, mh[c]); }
        int cnt = e - s;
        out[g * 256 + c] = cnt > 0 ? sum / (float)cnt : 0.f;
        out[g * 256 + 128 + c] = cnt > 0 ? mx : 0.f;
    }
}

// ---------------------------------------------------------------- launch

extern "C" void kernel_launch(void* const* d_in, const int* in_sizes, int n_in,
                              void* d_out, int out_size, void* d_ws, size_t ws_size,
                              hipStream_t stream) {
    const int N = N_NODES, E = N_EDGES, G = N_GRAPHS, E2 = E2_TOTAL;
    const float* x = (const float*)d_in[0];
    const int* ei = (const int*)d_in[1];
    const float* eattr = (const float*)d_in[2];
    const int* batch = (const int*)d_in[3];
    auto P = [&](int l, int k) { return (const float*)d_in[4 + l * 9 + k]; };
    // k: 0=Wl 1=bl 2=Wr 3=br 4=We 5=att 6=bo 7=lnw 8=lnb

    char* w = (char*)d_ws;
    size_t off = 0;
    auto alloc = [&](size_t bytes) -> void* {
        void* p = w + off;
        off += (bytes + 255) & ~(size_t)255;
        return p;
    };
    u16* XLbf = (u16*)alloc((size_t)N * 512 * 2);    // XL1 -> XL2 -> XL3 (bf16)
    float* B0 = (float*)alloc((size_t)N * 512 * 4);  // H1 -> H2 ; tail = H3
    float* XRf = (float*)alloc((size_t)N * 256 * 4); // XR2 -> XR3 (fp32)
    int* csr_src = (int*)alloc((size_t)E2 * 4);
    int* csr_eid = (int*)alloc((size_t)E2 * 4);
    int* rowptr = (int*)alloc((size_t)(N + 1) * 4);
    int* cursor = (int*)alloc((size_t)N * 4);
    int* deg = (int*)alloc((size_t)N * 4);
    float* lattr = (float*)alloc((size_t)N * 3 * 4);
    double* stats = (double*)alloc(6 * 8);
    int* gcnt = (int*)alloc((size_t)G * 4);
    int* goff = (int*)alloc((size_t)(G + 1) * 4);
    float* H3 = B0 + (size_t)N * 256;
    (void)ws_size; (void)n_in; (void)in_sizes; (void)out_size;

    hipMemsetAsync(deg, 0, (size_t)N * 4, stream);
    hipMemsetAsync(lattr, 0, (size_t)N * 3 * 4, stream);
    hipMemsetAsync(stats, 0, 6 * 8, stream);
    hipMemsetAsync(gcnt, 0, (size_t)G * 4, stream);

    deg_kernel<<<(E + 255) / 256, 256, 0, stream>>>(ei, eattr, deg, lattr, E);
    loopattr_kernel<<<(N + 255) / 256, 256, 0, stream>>>(deg, lattr, N);
    scan_kernel<<<1, 1024, 0, stream>>>(deg, rowptr, N);
    copy_kernel<<<(N + 255) / 256, 256, 0, stream>>>(rowptr, cursor, N);
    fill_kernel<<<(E2 + 255) / 256, 256, 0, stream>>>(ei, cursor, csr_src, csr_eid, E, E2);
    gcnt_kernel<<<(N + 255) / 256, 256, 0, stream>>>(batch, gcnt, N);
    gscan_kernel<<<1, 64, 0, stream>>>(gcnt, goff);

    // -------- layer 1 (din=8, H=4, HC=512): XL1 materialized bf16, xr recomputed
    xw8_kernel<<<(N + 63) / 64, 256, 0, stream>>>(x, P(0, 0), P(0, 1), XLbf, N);
    attn_fused<512, true><<<N, 256, 0, stream>>>(
        rowptr, csr_src, csr_eid, eattr, lattr, x,
        P(0, 2), P(0, 3), XLbf, nullptr,
        P(0, 4), P(0, 5), P(0, 6), B0, E);
    ln_stats<<<2048, 256, 0, stream>>>(B0, stats + 0, (size_t)N * 512);
    ln_apply_elu<<<2048, 256, 0, stream>>>(B0, stats + 0, P(0, 7), P(0, 8), 512,
                                           (size_t)N * 512);

    // -------- layer 2 (din=512, H=2, HC=256)
    {
        dim3 g((N + 127) / 128, 2);
        gemm_bias<true><<<g, 256, 0, stream>>>(B0, P(1, 0), P(1, 1), nullptr, XLbf, N, 512, 256);
        gemm_bias<false><<<g, 256, 0, stream>>>(B0, P(1, 2), P(1, 3), XRf, nullptr, N, 512, 256);
    }
    attn_fused<256, false><<<N, 256, 0, stream>>>(
        rowptr, csr_src, csr_eid, eattr, lattr, nullptr,
        nullptr, nullptr, XLbf, XRf,
        P(1, 4), P(1, 5), P(1, 6), B0, E);
    ln_stats<<<2048, 256, 0, stream>>>(B0, stats + 2, (size_t)N * 256);
    ln_apply_elu<<<2048, 256, 0, stream>>>(B0, stats + 2, P(1, 7), P(1, 8), 256,
                                           (size_t)N * 256);

    // -------- layer 3 (din=256, H=1, HC=128)
    {
        dim3 g((N + 127) / 128, 1);
        gemm_bias<true><<<g, 256, 0, stream>>>(B0, P(2, 0), P(2, 1), nullptr, XLbf, N, 256, 128);
        gemm_bias<false><<<g, 256, 0, stream>>>(B0, P(2, 2), P(2, 3), XRf, nullptr, N, 256, 128);
    }
    attn_fused<128, false><<<N, 256, 0, stream>>>(
        rowptr, csr_src, csr_eid, eattr, lattr, nullptr,
        nullptr, nullptr, XLbf, XRf,
        P(2, 4), P(2, 5), P(2, 6), H3, E);
    ln_stats<<<2048, 256, 0, stream>>>(H3, stats + 4, (size_t)N * 128);
    ln_apply_elu<<<2048, 256, 0, stream>>>(H3, stats + 4, P(2, 7), P(2, 8), 128,
                                           (size_t)N * 128);

    // -------- pooling (zero atomics)
    pool_kernel<<<G, 256, 0, stream>>>(H3, goff, (float*)d_out);
}

// Round 4
// 1834.086 us; speedup vs baseline: 2.0304x; 1.3559x over previous
//
#include <hip/hip_runtime.h>
#include <hip/hip_bf16.h>
#include <math.h>

#define N_NODES 50000
#define N_EDGES 800000
#define N_GRAPHS 64
#define E2_TOTAL (N_EDGES + N_NODES)

typedef unsigned short u16;

__device__ __forceinline__ u16 f2bf(float f) {
    unsigned u = __float_as_uint(f);
    u += 0x7fffu + ((u >> 16) & 1u);   // round-to-nearest-even
    return (u16)(u >> 16);
}
__device__ __forceinline__ float bf2f(u16 s) {
    return __uint_as_float((unsigned)s << 16);
}
// unpack packed pair of bf16 (low elem first in memory / low bits)
__device__ __forceinline__ void unpack2(unsigned v, float& a, float& b) {
    a = __uint_as_float(v << 16);
    b = __uint_as_float(v & 0xffff0000u);
}

// ---------------------------------------------------------------- CSR build

__global__ __launch_bounds__(256) void deg_kernel(const int* __restrict__ ei,
                                                  const float* __restrict__ eattr,
                                                  int* __restrict__ deg,
                                                  float* __restrict__ asum, int E) {
    int e = blockIdx.x * 256 + threadIdx.x;
    if (e >= E) return;
    int dst = ei[E + e];
    atomicAdd(&deg[dst], 1);
    atomicAdd(&asum[dst * 3 + 0], eattr[e * 3 + 0]);
    atomicAdd(&asum[dst * 3 + 1], eattr[e * 3 + 1]);
    atomicAdd(&asum[dst * 3 + 2], eattr[e * 3 + 2]);
}

__global__ __launch_bounds__(256) void loopattr_kernel(const int* __restrict__ deg,
                                                       float* __restrict__ asum, int N) {
    int n = blockIdx.x * 256 + threadIdx.x;
    if (n >= N) return;
    float inv = 1.0f / (float)max(deg[n], 1);
    asum[n * 3 + 0] *= inv;
    asum[n * 3 + 1] *= inv;
    asum[n * 3 + 2] *= inv;
}

__global__ __launch_bounds__(1024) void scan_kernel(const int* __restrict__ deg,
                                                    int* __restrict__ rowptr, int N) {
    __shared__ int wsum[16];
    __shared__ int carry_s;
    int tid = threadIdx.x, lane = tid & 63, wid = tid >> 6;
    if (tid == 0) carry_s = 0;
    __syncthreads();
    for (int base = 0; base < N; base += 1024) {
        int idx = base + tid;
        int v = (idx < N) ? deg[idx] + 1 : 0;
        int x = v;
        #pragma unroll
        for (int off = 1; off < 64; off <<= 1) {
            int t = __shfl_up(x, off);
            if (lane >= off) x += t;
        }
        if (lane == 63) wsum[wid] = x;
        __syncthreads();
        if (wid == 0) {
            int y = (lane < 16) ? wsum[lane] : 0;
            #pragma unroll
            for (int off = 1; off < 16; off <<= 1) {
                int t = __shfl_up(y, off);
                if (lane >= off) y += t;
            }
            if (lane < 16) wsum[lane] = y;
        }
        __syncthreads();
        int woff = (wid > 0) ? wsum[wid - 1] : 0;
        int incl = carry_s + woff + x;
        if (idx < N) rowptr[idx] = incl - v;  // exclusive
        __syncthreads();
        if (tid == 1023) carry_s += wsum[15];
        __syncthreads();
    }
    if (threadIdx.x == 0) rowptr[N] = carry_s;
}

__global__ __launch_bounds__(256) void copy_kernel(const int* __restrict__ a,
                                                   int* __restrict__ b, int N) {
    int n = blockIdx.x * 256 + threadIdx.x;
    if (n < N) b[n] = a[n];
}

// CSR fill: meta[pos] = {ea0, ea1, ea2, src-as-float-bits}
__global__ __launch_bounds__(256) void fill_kernel(const int* __restrict__ ei,
                                                   const float* __restrict__ eattr,
                                                   const float* __restrict__ lattr,
                                                   int* __restrict__ cursor,
                                                   float4* __restrict__ meta,
                                                   int E, int E2) {
    int e = blockIdx.x * 256 + threadIdx.x;
    if (e >= E2) return;
    int src, dst;
    float a0, a1, a2;
    if (e < E) {
        src = ei[e]; dst = ei[E + e];
        a0 = eattr[(size_t)e * 3 + 0];
        a1 = eattr[(size_t)e * 3 + 1];
        a2 = eattr[(size_t)e * 3 + 2];
    } else {
        src = e - E; dst = src;
        a0 = lattr[(size_t)dst * 3 + 0];
        a1 = lattr[(size_t)dst * 3 + 1];
        a2 = lattr[(size_t)dst * 3 + 2];
    }
    int pos = atomicAdd(&cursor[dst], 1);
    meta[pos] = make_float4(a0, a1, a2, __int_as_float(src));
}

// ---------------------------------------------------------------- X1 = x@W+b (din=8) -> bf16

__global__ __launch_bounds__(256) void xw8_kernel(const float* __restrict__ x,
                                                  const float* __restrict__ Wl,
                                                  const float* __restrict__ bl,
                                                  u16* __restrict__ XLbf, int N) {
    __shared__ float sW[8 * 512];
    __shared__ float sb[512];
    __shared__ float sx[64][8];
    int tid = threadIdx.x;
    int nb = blockIdx.x * 64;
    for (int i = tid; i < 8 * 512; i += 256) sW[i] = Wl[i];
    for (int i = tid; i < 512; i += 256) sb[i] = bl[i];
    for (int i = tid; i < 64 * 8; i += 256) {
        int j = i >> 3, k = i & 7;
        int n = nb + j;
        sx[j][k] = (n < N) ? x[(size_t)n * 8 + k] : 0.f;
    }
    __syncthreads();
    for (int it = 0; it < 64; it++) {
        int i = tid + it * 256;
        int j = i >> 8, c2 = (i & 255) * 2;
        int n = nb + j;
        if (n < N) {
            float v0 = sb[c2], v1 = sb[c2 + 1];
            #pragma unroll
            for (int k = 0; k < 8; k++) {
                v0 += sx[j][k] * sW[k * 512 + c2];
                v1 += sx[j][k] * sW[k * 512 + c2 + 1];
            }
            ushort2 o; o.x = f2bf(v0); o.y = f2bf(v1);
            *reinterpret_cast<ushort2*>(XLbf + (size_t)n * 512 + c2) = o;
        }
    }
}

// ---------------------------------------------------------------- GEMM (fp32 in, bf16 out)
// Y[N,M] = A[N,K] @ W[K,M] + bias ; 128x128 tile, BK=8, 256 thr, 8x8/thread

__global__ __launch_bounds__(256) void gemm_bias_bf(const float* __restrict__ A,
                                                    const float* __restrict__ W,
                                                    const float* __restrict__ bias,
                                                    u16* __restrict__ Yb,
                                                    int N, int K, int M) {
    __shared__ float As[8][132];
    __shared__ float Ws[8][132];
    int tid = threadIdx.x;
    int bm = blockIdx.x * 128, bn = blockIdx.y * 128;
    int tx = tid & 15, ty = tid >> 4;
    float acc[8][8] = {};
    int a_m = tid >> 1, a_k = (tid & 1) * 4;
    int w_k = tid >> 5, w_n = (tid & 31) * 4;
    for (int k0 = 0; k0 < K; k0 += 8) {
        int row = bm + a_m;
        float4 av = make_float4(0.f, 0.f, 0.f, 0.f);
        if (row < N) av = *reinterpret_cast<const float4*>(A + (size_t)row * K + k0 + a_k);
        As[a_k + 0][a_m] = av.x; As[a_k + 1][a_m] = av.y;
        As[a_k + 2][a_m] = av.z; As[a_k + 3][a_m] = av.w;
        float4 wv = *reinterpret_cast<const float4*>(W + (size_t)(k0 + w_k) * M + bn + w_n);
        *reinterpret_cast<float4*>(&Ws[w_k][w_n]) = wv;
        __syncthreads();
        #pragma unroll
        for (int k = 0; k < 8; k++) {
            float4 a0 = *reinterpret_cast<float4*>(&As[k][ty * 8]);
            float4 a1 = *reinterpret_cast<float4*>(&As[k][ty * 8 + 4]);
            float4 w0 = *reinterpret_cast<float4*>(&Ws[k][tx * 8]);
            float4 w1 = *reinterpret_cast<float4*>(&Ws[k][tx * 8 + 4]);
            float a[8] = {a0.x, a0.y, a0.z, a0.w, a1.x, a1.y, a1.z, a1.w};
            float b[8] = {w0.x, w0.y, w0.z, w0.w, w1.x, w1.y, w1.z, w1.w};
            #pragma unroll
            for (int i = 0; i < 8; i++)
                #pragma unroll
                for (int j = 0; j < 8; j++) acc[i][j] += a[i] * b[j];
        }
        __syncthreads();
    }
    #pragma unroll
    for (int i = 0; i < 8; i++) {
        int row = bm + ty * 8 + i;
        if (row < N) {
            u16 tmp[8];
            #pragma unroll
            for (int j = 0; j < 8; j++) tmp[j] = f2bf(acc[i][j] + bias[bn + tx * 8 + j]);
            *reinterpret_cast<uint4*>(Yb + (size_t)row * M + bn + tx * 8) =
                *reinterpret_cast<uint4*>(tmp);
        }
    }
}

// ---------------------------------------------------------------- wave-per-node GATv2
// One 64-lane wave owns one dst node. Lanes own CPL=HC/64 channels. Per edge:
// one uniform 16B meta load + one coalesced bf16 gather of the xl slice; logit
// via shfl reduce within the GS-lane head group; online softmax in registers.
// No LDS, no barriers.

template <int HC>
__global__ __launch_bounds__(256) void attn_wave(
    const int* __restrict__ rowptr, const float4* __restrict__ meta,
    const u16* __restrict__ XLbf, const u16* __restrict__ XRbf,
    const float* __restrict__ We, const float* __restrict__ att,
    const float* __restrict__ bo, float* __restrict__ out, int N) {
    constexpr int CPL = HC / 64;      // channels per lane (8/4/2)
    constexpr int GS = 128 / CPL;     // lanes per head group (16/32/64)
    int wid = threadIdx.x >> 6, lane = threadIdx.x & 63;
    int n = blockIdx.x * 4 + wid;
    if (n >= N) return;
    int cb = lane * CPL;

    float xr[CPL], we0[CPL], we1[CPL], we2[CPL], sa[CPL], acc[CPL];
    #pragma unroll
    for (int i = 0; i < CPL; i++) {
        we0[i] = We[cb + i];
        we1[i] = We[HC + cb + i];
        we2[i] = We[2 * HC + cb + i];
        sa[i]  = att[cb + i];
        acc[i] = 0.f;
    }
    {
        const u16* p = XRbf + (size_t)n * HC + cb;
        if constexpr (CPL == 8) {
            uint4 r = *reinterpret_cast<const uint4*>(p);
            unpack2(r.x, xr[0], xr[1]); unpack2(r.y, xr[2], xr[3]);
            unpack2(r.z, xr[4], xr[5]); unpack2(r.w, xr[6], xr[7]);
        } else if constexpr (CPL == 4) {
            uint2 r = *reinterpret_cast<const uint2*>(p);
            unpack2(r.x, xr[0], xr[1]); unpack2(r.y, xr[2], xr[3]);
        } else {
            unsigned r = *reinterpret_cast<const unsigned*>(p);
            unpack2(r, xr[0], xr[1]);
        }
    }

    float m = -INFINITY, l = 0.f;
    int beg = rowptr[n], end = rowptr[n + 1];
    for (int j = beg; j < end; j++) {
        float4 md = meta[j];
        int src = __float_as_int(md.w);
        float xl[CPL];
        {
            const u16* p = XLbf + (size_t)src * HC + cb;
            if constexpr (CPL == 8) {
                uint4 r = *reinterpret_cast<const uint4*>(p);
                unpack2(r.x, xl[0], xl[1]); unpack2(r.y, xl[2], xl[3]);
                unpack2(r.z, xl[4], xl[5]); unpack2(r.w, xl[6], xl[7]);
            } else if constexpr (CPL == 4) {
                uint2 r = *reinterpret_cast<const uint2*>(p);
                unpack2(r.x, xl[0], xl[1]); unpack2(r.y, xl[2], xl[3]);
            } else {
                unsigned r = *reinterpret_cast<const unsigned*>(p);
                unpack2(r, xl[0], xl[1]);
            }
        }
        float part = 0.f;
        #pragma unroll
        for (int i = 0; i < CPL; i++) {
            float ee = fmaf(md.x, we0[i], fmaf(md.y, we1[i], md.z * we2[i]));
            float u = xl[i] + xr[i] + ee;
            float lr = u > 0.f ? u : 0.2f * u;
            part = fmaf(lr, sa[i], part);
        }
        #pragma unroll
        for (int off = GS / 2; off >= 1; off >>= 1)
            part += __shfl_xor(part, off);
        float mn = fmaxf(m, part);
        float sc = __expf(m - mn);       // 0 on first edge (m = -inf)
        float w  = __expf(part - mn);
        l = l * sc + w;
        m = mn;
        #pragma unroll
        for (int i = 0; i < CPL; i++) acc[i] = fmaf(acc[i], sc, w * xl[i]);
    }
    float inv = 1.f / (l + 1e-16f);
    float o[CPL];
    #pragma unroll
    for (int i = 0; i < CPL; i++) o[i] = acc[i] * inv + bo[cb + i];
    float* q = out + (size_t)n * HC + cb;
    if constexpr (CPL == 8) {
        *reinterpret_cast<float4*>(q)     = make_float4(o[0], o[1], o[2], o[3]);
        *reinterpret_cast<float4*>(q + 4) = make_float4(o[4], o[5], o[6], o[7]);
    } else if constexpr (CPL == 4) {
        *reinterpret_cast<float4*>(q) = make_float4(o[0], o[1], o[2], o[3]);
    } else {
        *reinterpret_cast<float2*>(q) = make_float2(o[0], o[1]);
    }
}

// ---------------------------------------------------------------- layernorm

__global__ __launch_bounds__(256) void ln_stats(const float* __restrict__ x,
                                                double* __restrict__ stats, size_t count) {
    double s = 0.0, s2 = 0.0;
    for (size_t i = (size_t)blockIdx.x * 256 + threadIdx.x; i < count;
         i += (size_t)gridDim.x * 256) {
        double v = (double)x[i];
        s += v; s2 += v * v;
    }
    #pragma unroll
    for (int off = 32; off; off >>= 1) {
        s += __shfl_xor(s, off);
        s2 += __shfl_xor(s2, off);
    }
    __shared__ double wsh[4], wsh2[4];
    int wid = threadIdx.x >> 6, lane = threadIdx.x & 63;
    if (lane == 0) { wsh[wid] = s; wsh2[wid] = s2; }
    __syncthreads();
    if (threadIdx.x == 0) {
        double a = 0.0, b = 0.0;
        for (int w = 0; w < 4; w++) { a += wsh[w]; b += wsh2[w]; }
        atomicAdd(&stats[0], a);
        atomicAdd(&stats[1], b);
    }
}

__global__ __launch_bounds__(256) void ln_apply_elu(float* __restrict__ x,
                                                    const double* __restrict__ stats,
                                                    const float* __restrict__ w,
                                                    const float* __restrict__ b,
                                                    int F, size_t count) {
    double mu = stats[0] / (double)count;
    double var = stats[1] / (double)count - mu * mu;
    float sd = (float)sqrt(var > 0.0 ? var : 0.0);
    float rs = 1.f / (sd + 1e-5f);
    float muf = (float)mu;
    for (size_t i = (size_t)blockIdx.x * 256 + threadIdx.x; i < count;
         i += (size_t)gridDim.x * 256) {
        int c = (int)(i & (size_t)(F - 1));
        float v = (x[i] - muf) * rs * w[c] + b[c];
        x[i] = v > 0.f ? v : expm1f(v);
    }
}

// ---------------------------------------------------------------- pooling

__global__ __launch_bounds__(256) void gcnt_kernel(const int* __restrict__ batch,
                                                   int* __restrict__ gcnt, int N) {
    int n = blockIdx.x * 256 + threadIdx.x;
    if (n < N) atomicAdd(&gcnt[batch[n]], 1);
}

__global__ __launch_bounds__(64) void gscan_kernel(const int* __restrict__ gcnt,
                                                   int* __restrict__ goff) {
    int t = threadIdx.x;
    int x = gcnt[t];
    #pragma unroll
    for (int off = 1; off < 64; off <<= 1) {
        int v = __shfl_up(x, off);
        if (t >= off) x += v;
    }
    goff[t + 1] = x;
    if (t == 0) goff[0] = 0;
}

__global__ __launch_bounds__(256) void pool_kernel(const float* __restrict__ h,
                                                   const int* __restrict__ goff,
                                                   float* __restrict__ out) {
    __shared__ float sh[128], mh[128];
    int g = blockIdx.x;
    int s = goff[g], e = goff[g + 1];
    int tid = threadIdx.x;
    int c = tid & 127, part = tid >> 7;
    float sum = 0.f, mx = -INFINITY;
    for (int n = s + part; n < e; n += 2) {
        float v = h[(size_t)n * 128 + c];
        sum += v;
        mx = fmaxf(mx, v);
    }
    if (part == 1) { sh[c] = sum; mh[c] = mx; }
    __syncthreads();
    if (part == 0) {
        if (e - s > 1) { sum += sh[c]; mx = fmaxf(mx, mh[c]); }
        int cnt = e - s;
        out[g * 256 + c] = cnt > 0 ? sum / (float)cnt : 0.f;
        out[g * 256 + 128 + c] = cnt > 0 ? mx : 0.f;
    }
}

// ---------------------------------------------------------------- launch

extern "C" void kernel_launch(void* const* d_in, const int* in_sizes, int n_in,
                              void* d_out, int out_size, void* d_ws, size_t ws_size,
                              hipStream_t stream) {
    const int N = N_NODES, E = N_EDGES, G = N_GRAPHS, E2 = E2_TOTAL;
    const float* x = (const float*)d_in[0];
    const int* ei = (const int*)d_in[1];
    const float* eattr = (const float*)d_in[2];
    const int* batch = (const int*)d_in[3];
    auto P = [&](int l, int k) { return (const float*)d_in[4 + l * 9 + k]; };
    // k: 0=Wl 1=bl 2=Wr 3=br 4=We 5=att 6=bo 7=lnw 8=lnb

    char* w = (char*)d_ws;
    size_t off = 0;
    auto alloc = [&](size_t bytes) -> void* {
        void* p = w + off;
        off += (bytes + 255) & ~(size_t)255;
        return p;
    };
    u16* XLbf = (u16*)alloc((size_t)N * 512 * 2);    // XL (bf16), per layer
    u16* XRbf = (u16*)alloc((size_t)N * 512 * 2);    // XR (bf16), per layer
    float* B0 = (float*)alloc((size_t)N * 512 * 4);  // H1 -> H2 ; tail = H3
    float4* meta = (float4*)alloc((size_t)E2 * 16);  // CSR-ordered {ea, src}
    int* rowptr = (int*)alloc((size_t)(N + 1) * 4);
    int* cursor = (int*)alloc((size_t)N * 4);
    int* deg = (int*)alloc((size_t)N * 4);
    float* lattr = (float*)alloc((size_t)N * 3 * 4);
    double* stats = (double*)alloc(6 * 8);
    int* gcnt = (int*)alloc((size_t)G * 4);
    int* goff = (int*)alloc((size_t)(G + 1) * 4);
    float* H3 = B0 + (size_t)N * 256;
    (void)ws_size; (void)n_in; (void)in_sizes; (void)out_size;

    hipMemsetAsync(deg, 0, (size_t)N * 4, stream);
    hipMemsetAsync(lattr, 0, (size_t)N * 3 * 4, stream);
    hipMemsetAsync(stats, 0, 6 * 8, stream);
    hipMemsetAsync(gcnt, 0, (size_t)G * 4, stream);

    deg_kernel<<<(E + 255) / 256, 256, 0, stream>>>(ei, eattr, deg, lattr, E);
    loopattr_kernel<<<(N + 255) / 256, 256, 0, stream>>>(deg, lattr, N);
    scan_kernel<<<1, 1024, 0, stream>>>(deg, rowptr, N);
    copy_kernel<<<(N + 255) / 256, 256, 0, stream>>>(rowptr, cursor, N);
    fill_kernel<<<(E2 + 255) / 256, 256, 0, stream>>>(ei, eattr, lattr, cursor,
                                                      meta, E, E2);
    gcnt_kernel<<<(N + 255) / 256, 256, 0, stream>>>(batch, gcnt, N);
    gscan_kernel<<<1, 64, 0, stream>>>(gcnt, goff);

    int agrid = (N + 3) / 4;

    // -------- layer 1 (din=8, H=4, HC=512)
    xw8_kernel<<<(N + 63) / 64, 256, 0, stream>>>(x, P(0, 0), P(0, 1), XLbf, N);
    xw8_kernel<<<(N + 63) / 64, 256, 0, stream>>>(x, P(0, 2), P(0, 3), XRbf, N);
    attn_wave<512><<<agrid, 256, 0, stream>>>(rowptr, meta, XLbf, XRbf,
                                              P(0, 4), P(0, 5), P(0, 6), B0, N);
    ln_stats<<<2048, 256, 0, stream>>>(B0, stats + 0, (size_t)N * 512);
    ln_apply_elu<<<2048, 256, 0, stream>>>(B0, stats + 0, P(0, 7), P(0, 8), 512,
                                           (size_t)N * 512);

    // -------- layer 2 (din=512, H=2, HC=256)
    {
        dim3 g((N + 127) / 128, 2);
        gemm_bias_bf<<<g, 256, 0, stream>>>(B0, P(1, 0), P(1, 1), XLbf, N, 512, 256);
        gemm_bias_bf<<<g, 256, 0, stream>>>(B0, P(1, 2), P(1, 3), XRbf, N, 512, 256);
    }
    attn_wave<256><<<agrid, 256, 0, stream>>>(rowptr, meta, XLbf, XRbf,
                                              P(1, 4), P(1, 5), P(1, 6), B0, N);
    ln_stats<<<2048, 256, 0, stream>>>(B0, stats + 2, (size_t)N * 256);
    ln_apply_elu<<<2048, 256, 0, stream>>>(B0, stats + 2, P(1, 7), P(1, 8), 256,
                                           (size_t)N * 256);

    // -------- layer 3 (din=256, H=1, HC=128)
    {
        dim3 g((N + 127) / 128, 1);
        gemm_bias_bf<<<g, 256, 0, stream>>>(B0, P(2, 0), P(2, 1), XLbf, N, 256, 128);
        gemm_bias_bf<<<g, 256, 0, stream>>>(B0, P(2, 2), P(2, 3), XRbf, N, 256, 128);
    }
    attn_wave<128><<<agrid, 256, 0, stream>>>(rowptr, meta, XLbf, XRbf,
                                              P(2, 4), P(2, 5), P(2, 6), H3, N);
    ln_stats<<<2048, 256, 0, stream>>>(H3, stats + 4, (size_t)N * 128);
    ln_apply_elu<<<2048, 256, 0, stream>>>(H3, stats + 4, P(2, 7), P(2, 8), 128,
                                           (size_t)N * 128);

    // -------- pooling (zero atomics)
    pool_kernel<<<G, 256, 0, stream>>>(H3, goff, (float*)d_out);
}

// Round 5
// 1267.787 us; speedup vs baseline: 2.9374x; 1.4467x over previous
//
#include <hip/hip_runtime.h>
#include <hip/hip_bf16.h>
#include <math.h>

#define N_NODES 50000
#define N_EDGES 800000
#define N_GRAPHS 64
#define E2_TOTAL (N_EDGES + N_NODES)

typedef unsigned short u16;
typedef __attribute__((ext_vector_type(8))) short s16x8;
typedef __attribute__((ext_vector_type(4))) float f32x4;

__device__ __forceinline__ u16 f2bf(float f) {
    unsigned u = __float_as_uint(f);
    u += 0x7fffu + ((u >> 16) & 1u);   // round-to-nearest-even
    return (u16)(u >> 16);
}
__device__ __forceinline__ float bf2f(u16 s) {
    return __uint_as_float((unsigned)s << 16);
}
__device__ __forceinline__ void unpack2(unsigned v, float& a, float& b) {
    a = __uint_as_float(v << 16);
    b = __uint_as_float(v & 0xffff0000u);
}
__device__ __forceinline__ unsigned pack2(float a, float b) {
    return (unsigned)f2bf(a) | ((unsigned)f2bf(b) << 16);
}

// ---------------------------------------------------------------- CSR build

__global__ __launch_bounds__(256) void deg_kernel(const int* __restrict__ ei,
                                                  const float* __restrict__ eattr,
                                                  int* __restrict__ deg,
                                                  float* __restrict__ asum, int E) {
    int e = blockIdx.x * 256 + threadIdx.x;
    if (e >= E) return;
    int dst = ei[E + e];
    atomicAdd(&deg[dst], 1);
    atomicAdd(&asum[dst * 3 + 0], eattr[e * 3 + 0]);
    atomicAdd(&asum[dst * 3 + 1], eattr[e * 3 + 1]);
    atomicAdd(&asum[dst * 3 + 2], eattr[e * 3 + 2]);
}

__global__ __launch_bounds__(256) void loopattr_kernel(const int* __restrict__ deg,
                                                       float* __restrict__ asum, int N) {
    int n = blockIdx.x * 256 + threadIdx.x;
    if (n >= N) return;
    float inv = 1.0f / (float)max(deg[n], 1);
    asum[n * 3 + 0] *= inv;
    asum[n * 3 + 1] *= inv;
    asum[n * 3 + 2] *= inv;
}

__global__ __launch_bounds__(1024) void scan_kernel(const int* __restrict__ deg,
                                                    int* __restrict__ rowptr, int N) {
    __shared__ int wsum[16];
    __shared__ int carry_s;
    int tid = threadIdx.x, lane = tid & 63, wid = tid >> 6;
    if (tid == 0) carry_s = 0;
    __syncthreads();
    for (int base = 0; base < N; base += 1024) {
        int idx = base + tid;
        int v = (idx < N) ? deg[idx] + 1 : 0;
        int x = v;
        #pragma unroll
        for (int off = 1; off < 64; off <<= 1) {
            int t = __shfl_up(x, off);
            if (lane >= off) x += t;
        }
        if (lane == 63) wsum[wid] = x;
        __syncthreads();
        if (wid == 0) {
            int y = (lane < 16) ? wsum[lane] : 0;
            #pragma unroll
            for (int off = 1; off < 16; off <<= 1) {
                int t = __shfl_up(y, off);
                if (lane >= off) y += t;
            }
            if (lane < 16) wsum[lane] = y;
        }
        __syncthreads();
        int woff = (wid > 0) ? wsum[wid - 1] : 0;
        int incl = carry_s + woff + x;
        if (idx < N) rowptr[idx] = incl - v;  // exclusive
        __syncthreads();
        if (tid == 1023) carry_s += wsum[15];
        __syncthreads();
    }
    if (threadIdx.x == 0) rowptr[N] = carry_s;
}

__global__ __launch_bounds__(256) void copy_kernel(const int* __restrict__ a,
                                                   int* __restrict__ b, int N) {
    int n = blockIdx.x * 256 + threadIdx.x;
    if (n < N) b[n] = a[n];
}

// CSR fill: meta[pos] = {ea0, ea1, ea2, src-as-float-bits}
__global__ __launch_bounds__(256) void fill_kernel(const int* __restrict__ ei,
                                                   const float* __restrict__ eattr,
                                                   const float* __restrict__ lattr,
                                                   int* __restrict__ cursor,
                                                   float4* __restrict__ meta,
                                                   int E, int E2) {
    int e = blockIdx.x * 256 + threadIdx.x;
    if (e >= E2) return;
    int src, dst;
    float a0, a1, a2;
    if (e < E) {
        src = ei[e]; dst = ei[E + e];
        a0 = eattr[(size_t)e * 3 + 0];
        a1 = eattr[(size_t)e * 3 + 1];
        a2 = eattr[(size_t)e * 3 + 2];
    } else {
        src = e - E; dst = src;
        a0 = lattr[(size_t)dst * 3 + 0];
        a1 = lattr[(size_t)dst * 3 + 1];
        a2 = lattr[(size_t)dst * 3 + 2];
    }
    int pos = atomicAdd(&cursor[dst], 1);
    meta[pos] = make_float4(a0, a1, a2, __int_as_float(src));
}

// goff via binary search (batch is sorted) — replaces atomic gcnt + scan
__global__ __launch_bounds__(128) void goff_kernel(const int* __restrict__ batch,
                                                   int* __restrict__ goff, int N, int G) {
    int g = threadIdx.x;
    if (g > G) return;
    int lo = 0, hi = N;
    while (lo < hi) {
        int mid = (lo + hi) >> 1;
        if (batch[mid] < g) lo = mid + 1; else hi = mid;
    }
    goff[g] = lo;
}

// ---------------------------------------------------------------- X1 = x@W+b (din=8) -> bf16

__global__ __launch_bounds__(256) void xw8_kernel(const float* __restrict__ x,
                                                  const float* __restrict__ Wl,
                                                  const float* __restrict__ bl,
                                                  u16* __restrict__ XLbf, int N) {
    __shared__ float sW[8 * 512];
    __shared__ float sb[512];
    __shared__ float sx[64][8];
    int tid = threadIdx.x;
    int nb = blockIdx.x * 64;
    for (int i = tid; i < 8 * 512; i += 256) sW[i] = Wl[i];
    for (int i = tid; i < 512; i += 256) sb[i] = bl[i];
    for (int i = tid; i < 64 * 8; i += 256) {
        int j = i >> 3, k = i & 7;
        int n = nb + j;
        sx[j][k] = (n < N) ? x[(size_t)n * 8 + k] : 0.f;
    }
    __syncthreads();
    for (int it = 0; it < 64; it++) {
        int i = tid + it * 256;
        int j = i >> 8, c2 = (i & 255) * 2;
        int n = nb + j;
        if (n < N) {
            float v0 = sb[c2], v1 = sb[c2 + 1];
            #pragma unroll
            for (int k = 0; k < 8; k++) {
                v0 += sx[j][k] * sW[k * 512 + c2];
                v1 += sx[j][k] * sW[k * 512 + c2 + 1];
            }
            *reinterpret_cast<unsigned*>(XLbf + (size_t)n * 512 + c2) = pack2(v0, v1);
        }
    }
}

// ---------------------------------------------------------------- W -> Wt bf16 transpose
// W fp32 [K,M] -> Wt bf16 [M,K]

__global__ __launch_bounds__(256) void wt_kernel(const float* __restrict__ W,
                                                 u16* __restrict__ Wt, int K, int M) {
    __shared__ u16 t[64][65];
    int kb = blockIdx.x * 64, mb = blockIdx.y * 64;
    int tid = threadIdx.x;
    for (int i = tid; i < 64 * 64; i += 256) {
        int k = i >> 6, m = i & 63;   // m fastest -> coalesced read
        t[m][k] = f2bf(W[(size_t)(kb + k) * M + mb + m]);
    }
    __syncthreads();
    for (int i = tid; i < 64 * 64; i += 256) {
        int m = i >> 6, k = i & 63;   // k fastest -> coalesced write
        Wt[(size_t)(mb + m) * K + kb + k] = t[m][k];
    }
}

// ---------------------------------------------------------------- MFMA GEMM (bf16)
// Y[N,M] = A[N,K] @ Wt[M,K]^T + bias  (all bf16, fp32 accum)
// 128x128 tile, BK=64, 4 waves (2x2), each wave 64x64 via 4x4 frags of 16x16x32.

__global__ __launch_bounds__(256) void gemm_mfma(const u16* __restrict__ A,
                                                 const u16* __restrict__ Bt,
                                                 const float* __restrict__ bias,
                                                 u16* __restrict__ Y,
                                                 int N, int K, int M) {
    constexpr int BM = 128, BK = 64;
    __shared__ u16 As[BM][BK + 8];   // stride 144B, 16B-aligned, 2-way max alias
    __shared__ u16 Bs[BM][BK + 8];
    int tid = threadIdx.x;
    int wid = tid >> 6, lane = tid & 63;
    int wm = (wid >> 1) * 64, wn = (wid & 1) * 64;
    int bm = blockIdx.x * BM, bn = blockIdx.y * BM;
    int l15 = lane & 15, l4 = lane >> 4;
    f32x4 acc[4][4] = {};
    int sr = tid >> 3;            // 0..31
    int sc = (tid & 7) * 8;       // 0..56

    for (int k0 = 0; k0 < K; k0 += BK) {
        #pragma unroll
        for (int p = 0; p < 4; p++) {
            int r = p * 32 + sr;
            int grow = bm + r;
            uint4 av = make_uint4(0, 0, 0, 0);
            if (grow < N)
                av = *reinterpret_cast<const uint4*>(A + (size_t)grow * K + k0 + sc);
            *reinterpret_cast<uint4*>(&As[r][sc]) = av;
            uint4 bv = *reinterpret_cast<const uint4*>(Bt + (size_t)(bn + r) * K + k0 + sc);
            *reinterpret_cast<uint4*>(&Bs[r][sc]) = bv;
        }
        __syncthreads();
        #pragma unroll
        for (int kk = 0; kk < 2; kk++) {
            int kof = kk * 32 + l4 * 8;
            s16x8 af[4], bfr[4];
            #pragma unroll
            for (int i = 0; i < 4; i++) {
                af[i]  = *reinterpret_cast<const s16x8*>(&As[wm + i * 16 + l15][kof]);
                bfr[i] = *reinterpret_cast<const s16x8*>(&Bs[wn + i * 16 + l15][kof]);
            }
            #pragma unroll
            for (int i = 0; i < 4; i++)
                #pragma unroll
                for (int j = 0; j < 4; j++)
                    acc[i][j] = __builtin_amdgcn_mfma_f32_16x16x32_bf16(
                        af[i], bfr[j], acc[i][j], 0, 0, 0);
        }
        __syncthreads();
    }
    #pragma unroll
    for (int i = 0; i < 4; i++) {
        #pragma unroll
        for (int j = 0; j < 4; j++) {
            int col = bn + wn + j * 16 + l15;
            float bv = bias[col];
            #pragma unroll
            for (int r = 0; r < 4; r++) {
                int row = bm + wm + i * 16 + l4 * 4 + r;
                if (row < N)
                    Y[(size_t)row * M + col] = f2bf(acc[i][j][r] + bv);
            }
        }
    }
}

// ---------------------------------------------------------------- wave-per-node GATv2
// One 64-lane wave per dst node; lanes own CPL channels; zero LDS/barriers.

template <int HC, bool F32OUT>
__global__ __launch_bounds__(256) void attn_wave(
    const int* __restrict__ rowptr, const float4* __restrict__ meta,
    const u16* __restrict__ XLbf, const u16* __restrict__ XRbf,
    const float* __restrict__ We, const float* __restrict__ att,
    const float* __restrict__ bo, float* __restrict__ outf,
    u16* __restrict__ outb, int N) {
    constexpr int CPL = HC / 64;      // 8/4/2
    constexpr int GS = 128 / CPL;     // lanes per head group
    int wid = threadIdx.x >> 6, lane = threadIdx.x & 63;
    int n = blockIdx.x * 4 + wid;
    if (n >= N) return;
    int cb = lane * CPL;

    float xr[CPL], we0[CPL], we1[CPL], we2[CPL], sa[CPL], acc[CPL];
    #pragma unroll
    for (int i = 0; i < CPL; i++) {
        we0[i] = We[cb + i];
        we1[i] = We[HC + cb + i];
        we2[i] = We[2 * HC + cb + i];
        sa[i]  = att[cb + i];
        acc[i] = 0.f;
    }
    {
        const u16* p = XRbf + (size_t)n * HC + cb;
        if constexpr (CPL == 8) {
            uint4 r = *reinterpret_cast<const uint4*>(p);
            unpack2(r.x, xr[0], xr[1]); unpack2(r.y, xr[2], xr[3]);
            unpack2(r.z, xr[4], xr[5]); unpack2(r.w, xr[6], xr[7]);
        } else if constexpr (CPL == 4) {
            uint2 r = *reinterpret_cast<const uint2*>(p);
            unpack2(r.x, xr[0], xr[1]); unpack2(r.y, xr[2], xr[3]);
        } else {
            unsigned r = *reinterpret_cast<const unsigned*>(p);
            unpack2(r, xr[0], xr[1]);
        }
    }

    float m = -INFINITY, l = 0.f;
    int beg = rowptr[n], end = rowptr[n + 1];
    for (int j = beg; j < end; j++) {
        float4 md = meta[j];
        int src = __float_as_int(md.w);
        float xl[CPL];
        {
            const u16* p = XLbf + (size_t)src * HC + cb;
            if constexpr (CPL == 8) {
                uint4 r = *reinterpret_cast<const uint4*>(p);
                unpack2(r.x, xl[0], xl[1]); unpack2(r.y, xl[2], xl[3]);
                unpack2(r.z, xl[4], xl[5]); unpack2(r.w, xl[6], xl[7]);
            } else if constexpr (CPL == 4) {
                uint2 r = *reinterpret_cast<const uint2*>(p);
                unpack2(r.x, xl[0], xl[1]); unpack2(r.y, xl[2], xl[3]);
            } else {
                unsigned r = *reinterpret_cast<const unsigned*>(p);
                unpack2(r, xl[0], xl[1]);
            }
        }
        float part = 0.f;
        #pragma unroll
        for (int i = 0; i < CPL; i++) {
            float ee = fmaf(md.x, we0[i], fmaf(md.y, we1[i], md.z * we2[i]));
            float u = xl[i] + xr[i] + ee;
            float lr = u > 0.f ? u : 0.2f * u;
            part = fmaf(lr, sa[i], part);
        }
        #pragma unroll
        for (int off = GS / 2; off >= 1; off >>= 1)
            part += __shfl_xor(part, off);
        float mn = fmaxf(m, part);
        float sc = __expf(m - mn);
        float w  = __expf(part - mn);
        l = l * sc + w;
        m = mn;
        #pragma unroll
        for (int i = 0; i < CPL; i++) acc[i] = fmaf(acc[i], sc, w * xl[i]);
    }
    float inv = 1.f / (l + 1e-16f);
    float o[CPL];
    #pragma unroll
    for (int i = 0; i < CPL; i++) o[i] = acc[i] * inv + bo[cb + i];
    if constexpr (F32OUT) {
        float* q = outf + (size_t)n * HC + cb;
        if constexpr (CPL == 8) {
            *reinterpret_cast<float4*>(q)     = make_float4(o[0], o[1], o[2], o[3]);
            *reinterpret_cast<float4*>(q + 4) = make_float4(o[4], o[5], o[6], o[7]);
        } else if constexpr (CPL == 4) {
            *reinterpret_cast<float4*>(q) = make_float4(o[0], o[1], o[2], o[3]);
        } else {
            *reinterpret_cast<float2*>(q) = make_float2(o[0], o[1]);
        }
    } else {
        u16* q = outb + (size_t)n * HC + cb;
        if constexpr (CPL == 8) {
            *reinterpret_cast<uint4*>(q) =
                make_uint4(pack2(o[0], o[1]), pack2(o[2], o[3]),
                           pack2(o[4], o[5]), pack2(o[6], o[7]));
        } else if constexpr (CPL == 4) {
            *reinterpret_cast<uint2*>(q) =
                make_uint2(pack2(o[0], o[1]), pack2(o[2], o[3]));
        } else {
            *reinterpret_cast<unsigned*>(q) = pack2(o[0], o[1]);
        }
    }
}

// ---------------------------------------------------------------- layernorm (bf16 / fp32)

__global__ __launch_bounds__(256) void ln_stats_bf(const u16* __restrict__ x,
                                                   double* __restrict__ stats,
                                                   size_t count) {
    double s = 0.0, s2 = 0.0;
    size_t stride = (size_t)gridDim.x * 256 * 8;
    for (size_t i = ((size_t)blockIdx.x * 256 + threadIdx.x) * 8; i < count; i += stride) {
        uint4 v = *reinterpret_cast<const uint4*>(x + i);
        float f[8];
        unpack2(v.x, f[0], f[1]); unpack2(v.y, f[2], f[3]);
        unpack2(v.z, f[4], f[5]); unpack2(v.w, f[6], f[7]);
        float ps = 0.f, ps2 = 0.f;
        #pragma unroll
        for (int k = 0; k < 8; k++) { ps += f[k]; ps2 += f[k] * f[k]; }
        s += (double)ps; s2 += (double)ps2;
    }
    #pragma unroll
    for (int off = 32; off; off >>= 1) {
        s += __shfl_xor(s, off);
        s2 += __shfl_xor(s2, off);
    }
    __shared__ double wsh[4], wsh2[4];
    int wid = threadIdx.x >> 6, lane = threadIdx.x & 63;
    if (lane == 0) { wsh[wid] = s; wsh2[wid] = s2; }
    __syncthreads();
    if (threadIdx.x == 0) {
        double a = 0.0, b = 0.0;
        for (int w = 0; w < 4; w++) { a += wsh[w]; b += wsh2[w]; }
        atomicAdd(&stats[0], a);
        atomicAdd(&stats[1], b);
    }
}

__global__ __launch_bounds__(256) void ln_apply_elu_bf(u16* __restrict__ x,
                                                       const double* __restrict__ stats,
                                                       const float* __restrict__ w,
                                                       const float* __restrict__ b,
                                                       int F, size_t count) {
    double mu = stats[0] / (double)count;
    double var = stats[1] / (double)count - mu * mu;
    float sd = (float)sqrt(var > 0.0 ? var : 0.0);
    float rs = 1.f / (sd + 1e-5f);
    float muf = (float)mu;
    size_t stride = (size_t)gridDim.x * 256 * 8;
    for (size_t i = ((size_t)blockIdx.x * 256 + threadIdx.x) * 8; i < count; i += stride) {
        uint4 v = *reinterpret_cast<const uint4*>(x + i);
        float f[8];
        unpack2(v.x, f[0], f[1]); unpack2(v.y, f[2], f[3]);
        unpack2(v.z, f[4], f[5]); unpack2(v.w, f[6], f[7]);
        int c = (int)(i & (size_t)(F - 1));
        #pragma unroll
        for (int k = 0; k < 8; k++) {
            float u = (f[k] - muf) * rs * w[c + k] + b[c + k];
            f[k] = u > 0.f ? u : expm1f(u);
        }
        uint4 o = make_uint4(pack2(f[0], f[1]), pack2(f[2], f[3]),
                             pack2(f[4], f[5]), pack2(f[6], f[7]));
        *reinterpret_cast<uint4*>(x + i) = o;
    }
}

__global__ __launch_bounds__(256) void ln_stats_f32(const float* __restrict__ x,
                                                    double* __restrict__ stats,
                                                    size_t count) {
    double s = 0.0, s2 = 0.0;
    size_t stride = (size_t)gridDim.x * 256 * 4;
    for (size_t i = ((size_t)blockIdx.x * 256 + threadIdx.x) * 4; i < count; i += stride) {
        float4 v = *reinterpret_cast<const float4*>(x + i);
        s += (double)v.x + (double)v.y + (double)v.z + (double)v.w;
        s2 += (double)v.x * v.x + (double)v.y * v.y +
              (double)v.z * v.z + (double)v.w * v.w;
    }
    #pragma unroll
    for (int off = 32; off; off >>= 1) {
        s += __shfl_xor(s, off);
        s2 += __shfl_xor(s2, off);
    }
    __shared__ double wsh[4], wsh2[4];
    int wid = threadIdx.x >> 6, lane = threadIdx.x & 63;
    if (lane == 0) { wsh[wid] = s; wsh2[wid] = s2; }
    __syncthreads();
    if (threadIdx.x == 0) {
        double a = 0.0, b = 0.0;
        for (int w = 0; w < 4; w++) { a += wsh[w]; b += wsh2[w]; }
        atomicAdd(&stats[0], a);
        atomicAdd(&stats[1], b);
    }
}

__global__ __launch_bounds__(256) void ln_apply_elu_f32(float* __restrict__ x,
                                                        const double* __restrict__ stats,
                                                        const float* __restrict__ w,
                                                        const float* __restrict__ b,
                                                        int F, size_t count) {
    double mu = stats[0] / (double)count;
    double var = stats[1] / (double)count - mu * mu;
    float sd = (float)sqrt(var > 0.0 ? var : 0.0);
    float rs = 1.f / (sd + 1e-5f);
    float muf = (float)mu;
    for (size_t i = (size_t)blockIdx.x * 256 + threadIdx.x; i < count;
         i += (size_t)gridDim.x * 256) {
        int c = (int)(i & (size_t)(F - 1));
        float v = (x[i] - muf) * rs * w[c] + b[c];
        x[i] = v > 0.f ? v : expm1f(v);
    }
}

// ---------------------------------------------------------------- pooling

__global__ __launch_bounds__(256) void pool_kernel(const float* __restrict__ h,
                                                   const int* __restrict__ goff,
                                                   float* __restrict__ out) {
    __shared__ float sh[128], mh[128];
    int g = blockIdx.x;
    int s = goff[g], e = goff[g + 1];
    int tid = threadIdx.x;
    int c = tid & 127, part = tid >> 7;
    float sum = 0.f, mx = -INFINITY;
    for (int n = s + part; n < e; n += 2) {
        float v = h[(size_t)n * 128 + c];
        sum += v;
        mx = fmaxf(mx, v);
    }
    if (part == 1) { sh[c] = sum; mh[c] = mx; }
    __syncthreads();
    if (part == 0) {
        if (e - s > 1) { sum += sh[c]; mx = fmaxf(mx, mh[c]); }
        int cnt = e - s;
        out[g * 256 + c] = cnt > 0 ? sum / (float)cnt : 0.f;
        out[g * 256 + 128 + c] = cnt > 0 ? mx : 0.f;
    }
}

// ---------------------------------------------------------------- launch

extern "C" void kernel_launch(void* const* d_in, const int* in_sizes, int n_in,
                              void* d_out, int out_size, void* d_ws, size_t ws_size,
                              hipStream_t stream) {
    const int N = N_NODES, E = N_EDGES, G = N_GRAPHS, E2 = E2_TOTAL;
    const float* x = (const float*)d_in[0];
    const int* ei = (const int*)d_in[1];
    const float* eattr = (const float*)d_in[2];
    const int* batch = (const int*)d_in[3];
    auto P = [&](int l, int k) { return (const float*)d_in[4 + l * 9 + k]; };
    // k: 0=Wl 1=bl 2=Wr 3=br 4=We 5=att 6=bo 7=lnw 8=lnb

    char* w = (char*)d_ws;
    size_t off = 0;
    auto alloc = [&](size_t bytes) -> void* {
        void* p = w + off;
        off += (bytes + 255) & ~(size_t)255;
        return p;
    };
    u16* Xa = (u16*)alloc((size_t)N * 512 * 2);      // XL per layer
    u16* Xb = (u16*)alloc((size_t)N * 512 * 2);      // XR per layer
    u16* Xc = (u16*)alloc((size_t)N * 512 * 2);      // h (post-LN+ELU) per layer
    float* H3f = (float*)alloc((size_t)N * 128 * 4); // layer-3 output fp32
    float4* meta = (float4*)alloc((size_t)E2 * 16);  // CSR-ordered {ea, src}
    u16* WtL = (u16*)alloc((size_t)512 * 256 * 2);
    u16* WtR = (u16*)alloc((size_t)512 * 256 * 2);
    int* rowptr = (int*)alloc((size_t)(N + 1) * 4);
    int* cursor = (int*)alloc((size_t)N * 4);
    int* deg = (int*)alloc((size_t)N * 4);
    float* lattr = (float*)alloc((size_t)N * 3 * 4);
    double* stats = (double*)alloc(6 * 8);
    int* goff = (int*)alloc((size_t)(G + 1) * 4);
    (void)ws_size; (void)n_in; (void)in_sizes; (void)out_size;

    hipMemsetAsync(deg, 0, (size_t)N * 4, stream);
    hipMemsetAsync(lattr, 0, (size_t)N * 3 * 4, stream);
    hipMemsetAsync(stats, 0, 6 * 8, stream);

    deg_kernel<<<(E + 255) / 256, 256, 0, stream>>>(ei, eattr, deg, lattr, E);
    loopattr_kernel<<<(N + 255) / 256, 256, 0, stream>>>(deg, lattr, N);
    scan_kernel<<<1, 1024, 0, stream>>>(deg, rowptr, N);
    copy_kernel<<<(N + 255) / 256, 256, 0, stream>>>(rowptr, cursor, N);
    fill_kernel<<<(E2 + 255) / 256, 256, 0, stream>>>(ei, eattr, lattr, cursor,
                                                      meta, E, E2);
    goff_kernel<<<1, 128, 0, stream>>>(batch, goff, N, G);

    int agrid = (N + 3) / 4;

    // -------- layer 1 (din=8, H=4, HC=512)
    xw8_kernel<<<(N + 63) / 64, 256, 0, stream>>>(x, P(0, 0), P(0, 1), Xa, N);
    xw8_kernel<<<(N + 63) / 64, 256, 0, stream>>>(x, P(0, 2), P(0, 3), Xb, N);
    attn_wave<512, false><<<agrid, 256, 0, stream>>>(rowptr, meta, Xa, Xb,
                                                     P(0, 4), P(0, 5), P(0, 6),
                                                     nullptr, Xc, N);
    ln_stats_bf<<<1024, 256, 0, stream>>>(Xc, stats + 0, (size_t)N * 512);
    ln_apply_elu_bf<<<1024, 256, 0, stream>>>(Xc, stats + 0, P(0, 7), P(0, 8), 512,
                                              (size_t)N * 512);

    // -------- layer 2 (din=512, H=2, HC=256)
    {
        dim3 tg(512 / 64, 256 / 64);
        wt_kernel<<<tg, 256, 0, stream>>>(P(1, 0), WtL, 512, 256);
        wt_kernel<<<tg, 256, 0, stream>>>(P(1, 2), WtR, 512, 256);
        dim3 gg((N + 127) / 128, 2);
        gemm_mfma<<<gg, 256, 0, stream>>>(Xc, WtL, P(1, 1), Xa, N, 512, 256);
        gemm_mfma<<<gg, 256, 0, stream>>>(Xc, WtR, P(1, 3), Xb, N, 512, 256);
    }
    attn_wave<256, false><<<agrid, 256, 0, stream>>>(rowptr, meta, Xa, Xb,
                                                     P(1, 4), P(1, 5), P(1, 6),
                                                     nullptr, Xc, N);
    ln_stats_bf<<<1024, 256, 0, stream>>>(Xc, stats + 2, (size_t)N * 256);
    ln_apply_elu_bf<<<1024, 256, 0, stream>>>(Xc, stats + 2, P(1, 7), P(1, 8), 256,
                                              (size_t)N * 256);

    // -------- layer 3 (din=256, H=1, HC=128)
    {
        dim3 tg(256 / 64, 128 / 64);
        wt_kernel<<<tg, 256, 0, stream>>>(P(2, 0), WtL, 256, 128);
        wt_kernel<<<tg, 256, 0, stream>>>(P(2, 2), WtR, 256, 128);
        dim3 gg((N + 127) / 128, 1);
        gemm_mfma<<<gg, 256, 0, stream>>>(Xc, WtL, P(2, 1), Xa, N, 256, 128);
        gemm_mfma<<<gg, 256, 0, stream>>>(Xc, WtR, P(2, 3), Xb, N, 256, 128);
    }
    attn_wave<128, true><<<agrid, 256, 0, stream>>>(rowptr, meta, Xa, Xb,
                                                    P(2, 4), P(2, 5), P(2, 6),
                                                    H3f, nullptr, N);
    ln_stats_f32<<<1024, 256, 0, stream>>>(H3f, stats + 4, (size_t)N * 128);
    ln_apply_elu_f32<<<1024, 256, 0, stream>>>(H3f, stats + 4, P(2, 7), P(2, 8), 128,
                                               (size_t)N * 128);

    // -------- pooling
    pool_kernel<<<G, 256, 0, stream>>>(H3f, goff, (float*)d_out);
}

// Round 6
// 1131.199 us; speedup vs baseline: 3.2920x; 1.1207x over previous
//
#include <hip/hip_runtime.h>
#include <hip/hip_bf16.h>
#include <math.h>

#define N_NODES 50000
#define N_EDGES 800000
#define N_GRAPHS 64
#define E2_TOTAL (N_EDGES + N_NODES)

typedef unsigned short u16;
typedef __attribute__((ext_vector_type(8))) short s16x8;
typedef __attribute__((ext_vector_type(4))) float f32x4;

__device__ __forceinline__ u16 f2bf(float f) {
    unsigned u = __float_as_uint(f);
    u += 0x7fffu + ((u >> 16) & 1u);   // round-to-nearest-even
    return (u16)(u >> 16);
}
__device__ __forceinline__ float bf2f(u16 s) {
    return __uint_as_float((unsigned)s << 16);
}
__device__ __forceinline__ void unpack2(unsigned v, float& a, float& b) {
    a = __uint_as_float(v << 16);
    b = __uint_as_float(v & 0xffff0000u);
}
__device__ __forceinline__ unsigned pack2(float a, float b) {
    return (unsigned)f2bf(a) | ((unsigned)f2bf(b) << 16);
}

// ---------------------------------------------------------------- CSR build

__global__ __launch_bounds__(256) void deg_kernel(const int* __restrict__ ei,
                                                  const float* __restrict__ eattr,
                                                  int* __restrict__ deg,
                                                  float* __restrict__ asum, int E) {
    int e = blockIdx.x * 256 + threadIdx.x;
    if (e >= E) return;
    int dst = ei[E + e];
    atomicAdd(&deg[dst], 1);
    atomicAdd(&asum[dst * 3 + 0], eattr[e * 3 + 0]);
    atomicAdd(&asum[dst * 3 + 1], eattr[e * 3 + 1]);
    atomicAdd(&asum[dst * 3 + 2], eattr[e * 3 + 2]);
}

__global__ __launch_bounds__(256) void loopattr_kernel(const int* __restrict__ deg,
                                                       float* __restrict__ asum, int N) {
    int n = blockIdx.x * 256 + threadIdx.x;
    if (n >= N) return;
    float inv = 1.0f / (float)max(deg[n], 1);
    asum[n * 3 + 0] *= inv;
    asum[n * 3 + 1] *= inv;
    asum[n * 3 + 2] *= inv;
}

// exclusive scan of (deg+1); 4 elements per thread, single block of 1024
__global__ __launch_bounds__(1024) void scan_kernel(const int* __restrict__ deg,
                                                    int* __restrict__ rowptr, int N) {
    __shared__ int wsum[16];
    __shared__ int carry_s;
    int tid = threadIdx.x, lane = tid & 63, wid = tid >> 6;
    if (tid == 0) carry_s = 0;
    __syncthreads();
    for (int base = 0; base < N; base += 4096) {
        int i0 = base + tid * 4;
        int d0 = (i0 + 0 < N) ? deg[i0 + 0] + 1 : 0;
        int d1 = (i0 + 1 < N) ? deg[i0 + 1] + 1 : 0;
        int d2 = (i0 + 2 < N) ? deg[i0 + 2] + 1 : 0;
        int d3 = (i0 + 3 < N) ? deg[i0 + 3] + 1 : 0;
        int v = d0 + d1 + d2 + d3;
        int x = v;
        #pragma unroll
        for (int off = 1; off < 64; off <<= 1) {
            int t = __shfl_up(x, off);
            if (lane >= off) x += t;
        }
        if (lane == 63) wsum[wid] = x;
        __syncthreads();
        if (wid == 0) {
            int y = (lane < 16) ? wsum[lane] : 0;
            #pragma unroll
            for (int off = 1; off < 16; off <<= 1) {
                int t = __shfl_up(y, off);
                if (lane >= off) y += t;
            }
            if (lane < 16) wsum[lane] = y;
        }
        __syncthreads();
        int woff = (wid > 0) ? wsum[wid - 1] : 0;
        int excl = carry_s + woff + x - v;
        if (i0 + 0 < N) rowptr[i0 + 0] = excl;
        if (i0 + 1 < N) rowptr[i0 + 1] = excl + d0;
        if (i0 + 2 < N) rowptr[i0 + 2] = excl + d0 + d1;
        if (i0 + 3 < N) rowptr[i0 + 3] = excl + d0 + d1 + d2;
        __syncthreads();
        if (tid == 1023) carry_s += wsum[15];
        __syncthreads();
    }
    if (threadIdx.x == 0) rowptr[N] = carry_s;
}

__global__ __launch_bounds__(256) void copy_kernel(const int* __restrict__ a,
                                                   int* __restrict__ b, int N) {
    int n = blockIdx.x * 256 + threadIdx.x;
    if (n < N) b[n] = a[n];
}

// CSR fill: meta[pos] = {ea0, ea1, ea2, src-as-float-bits}
__global__ __launch_bounds__(256) void fill_kernel(const int* __restrict__ ei,
                                                   const float* __restrict__ eattr,
                                                   const float* __restrict__ lattr,
                                                   int* __restrict__ cursor,
                                                   float4* __restrict__ meta,
                                                   int E, int E2) {
    int e = blockIdx.x * 256 + threadIdx.x;
    if (e >= E2) return;
    int src, dst;
    float a0, a1, a2;
    if (e < E) {
        src = ei[e]; dst = ei[E + e];
        a0 = eattr[(size_t)e * 3 + 0];
        a1 = eattr[(size_t)e * 3 + 1];
        a2 = eattr[(size_t)e * 3 + 2];
    } else {
        src = e - E; dst = src;
        a0 = lattr[(size_t)dst * 3 + 0];
        a1 = lattr[(size_t)dst * 3 + 1];
        a2 = lattr[(size_t)dst * 3 + 2];
    }
    int pos = atomicAdd(&cursor[dst], 1);
    meta[pos] = make_float4(a0, a1, a2, __int_as_float(src));
}

// goff via binary search (batch is sorted)
__global__ __launch_bounds__(128) void goff_kernel(const int* __restrict__ batch,
                                                   int* __restrict__ goff, int N, int G) {
    int g = threadIdx.x;
    if (g > G) return;
    int lo = 0, hi = N;
    while (lo < hi) {
        int mid = (lo + hi) >> 1;
        if (batch[mid] < g) lo = mid + 1; else hi = mid;
    }
    goff[g] = lo;
}

// ---------------------------------------------------------------- X1 = x@W+b (din=8) -> bf16

__global__ __launch_bounds__(256) void xw8_kernel(const float* __restrict__ x,
                                                  const float* __restrict__ Wl,
                                                  const float* __restrict__ bl,
                                                  u16* __restrict__ XLbf, int N) {
    __shared__ float sW[8 * 512];
    __shared__ float sb[512];
    __shared__ float sx[64][8];
    int tid = threadIdx.x;
    int nb = blockIdx.x * 64;
    for (int i = tid; i < 8 * 512; i += 256) sW[i] = Wl[i];
    for (int i = tid; i < 512; i += 256) sb[i] = bl[i];
    for (int i = tid; i < 64 * 8; i += 256) {
        int j = i >> 3, k = i & 7;
        int n = nb + j;
        sx[j][k] = (n < N) ? x[(size_t)n * 8 + k] : 0.f;
    }
    __syncthreads();
    for (int it = 0; it < 64; it++) {
        int i = tid + it * 256;
        int j = i >> 8, c2 = (i & 255) * 2;
        int n = nb + j;
        if (n < N) {
            float v0 = sb[c2], v1 = sb[c2 + 1];
            #pragma unroll
            for (int k = 0; k < 8; k++) {
                v0 += sx[j][k] * sW[k * 512 + c2];
                v1 += sx[j][k] * sW[k * 512 + c2 + 1];
            }
            *reinterpret_cast<unsigned*>(XLbf + (size_t)n * 512 + c2) = pack2(v0, v1);
        }
    }
}

// ---------------------------------------------------------------- W -> Wt bf16 transpose

__global__ __launch_bounds__(256) void wt_kernel(const float* __restrict__ W,
                                                 u16* __restrict__ Wt, int K, int M) {
    __shared__ u16 t[64][65];
    int kb = blockIdx.x * 64, mb = blockIdx.y * 64;
    int tid = threadIdx.x;
    for (int i = tid; i < 64 * 64; i += 256) {
        int k = i >> 6, m = i & 63;
        t[m][k] = f2bf(W[(size_t)(kb + k) * M + mb + m]);
    }
    __syncthreads();
    for (int i = tid; i < 64 * 64; i += 256) {
        int m = i >> 6, k = i & 63;
        Wt[(size_t)(mb + m) * K + kb + k] = t[m][k];
    }
}

// ---------------------------------------------------------------- MFMA GEMM (bf16)

__global__ __launch_bounds__(256) void gemm_mfma(const u16* __restrict__ A,
                                                 const u16* __restrict__ Bt,
                                                 const float* __restrict__ bias,
                                                 u16* __restrict__ Y,
                                                 int N, int K, int M) {
    constexpr int BM = 128, BK = 64;
    __shared__ u16 As[BM][BK + 8];
    __shared__ u16 Bs[BM][BK + 8];
    int tid = threadIdx.x;
    int wid = tid >> 6, lane = tid & 63;
    int wm = (wid >> 1) * 64, wn = (wid & 1) * 64;
    int bm = blockIdx.x * BM, bn = blockIdx.y * BM;
    int l15 = lane & 15, l4 = lane >> 4;
    f32x4 acc[4][4] = {};
    int sr = tid >> 3;
    int sc = (tid & 7) * 8;

    for (int k0 = 0; k0 < K; k0 += BK) {
        #pragma unroll
        for (int p = 0; p < 4; p++) {
            int r = p * 32 + sr;
            int grow = bm + r;
            uint4 av = make_uint4(0, 0, 0, 0);
            if (grow < N)
                av = *reinterpret_cast<const uint4*>(A + (size_t)grow * K + k0 + sc);
            *reinterpret_cast<uint4*>(&As[r][sc]) = av;
            uint4 bv = *reinterpret_cast<const uint4*>(Bt + (size_t)(bn + r) * K + k0 + sc);
            *reinterpret_cast<uint4*>(&Bs[r][sc]) = bv;
        }
        __syncthreads();
        #pragma unroll
        for (int kk = 0; kk < 2; kk++) {
            int kof = kk * 32 + l4 * 8;
            s16x8 af[4], bfr[4];
            #pragma unroll
            for (int i = 0; i < 4; i++) {
                af[i]  = *reinterpret_cast<const s16x8*>(&As[wm + i * 16 + l15][kof]);
                bfr[i] = *reinterpret_cast<const s16x8*>(&Bs[wn + i * 16 + l15][kof]);
            }
            #pragma unroll
            for (int i = 0; i < 4; i++)
                #pragma unroll
                for (int j = 0; j < 4; j++)
                    acc[i][j] = __builtin_amdgcn_mfma_f32_16x16x32_bf16(
                        af[i], bfr[j], acc[i][j], 0, 0, 0);
        }
        __syncthreads();
    }
    #pragma unroll
    for (int i = 0; i < 4; i++) {
        #pragma unroll
        for (int j = 0; j < 4; j++) {
            int col = bn + wn + j * 16 + l15;
            float bv = bias[col];
            #pragma unroll
            for (int r = 0; r < 4; r++) {
                int row = bm + wm + i * 16 + l4 * 4 + r;
                if (row < N)
                    Y[(size_t)row * M + col] = f2bf(acc[i][j][r] + bv);
            }
        }
    }
}

// ---------------------------------------------------------------- wave-per-node GATv2
// SPLIT waves per node, each owning CW=HC/SPLIT channels (CPL per lane).
// 2-deep software pipeline on {meta, xl-gather}; defer-max online softmax.

template <int HC, int SPLIT, bool F32OUT>
__global__ __launch_bounds__(256) void attn_wave(
    const int* __restrict__ rowptr, const float4* __restrict__ meta,
    const u16* __restrict__ XLbf, const u16* __restrict__ XRbf,
    const float* __restrict__ We, const float* __restrict__ att,
    const float* __restrict__ bo, float* __restrict__ outf,
    u16* __restrict__ outb, int N) {
    constexpr int CW  = HC / SPLIT;   // channels per wave
    constexpr int CPL = CW / 64;      // 4 or 2
    constexpr int GS  = 128 / CPL;    // lanes per head group (32 or 64)
    int gw = blockIdx.x * 4 + (threadIdx.x >> 6);
    int lane = threadIdx.x & 63;
    int n = gw / SPLIT;
    int sub = gw - n * SPLIT;
    if (n >= N) return;
    int cb = sub * CW + lane * CPL;

    float xr[CPL], we0[CPL], we1[CPL], we2[CPL], sa[CPL], acc[CPL];
    #pragma unroll
    for (int i = 0; i < CPL; i++) {
        we0[i] = We[cb + i];
        we1[i] = We[HC + cb + i];
        we2[i] = We[2 * HC + cb + i];
        sa[i]  = att[cb + i];
        acc[i] = 0.f;
    }
    {
        const u16* p = XRbf + (size_t)n * HC + cb;
        if constexpr (CPL == 4) {
            uint2 r = *reinterpret_cast<const uint2*>(p);
            unpack2(r.x, xr[0], xr[1]); unpack2(r.y, xr[2], xr[3]);
        } else {
            unsigned r = *reinterpret_cast<const unsigned*>(p);
            unpack2(r, xr[0], xr[1]);
        }
    }

    auto ldxl = [&](int src) -> uint2 {
        const u16* p = XLbf + (size_t)src * HC + cb;
        if constexpr (CPL == 4) {
            return *reinterpret_cast<const uint2*>(p);
        } else {
            uint2 r; r.x = *reinterpret_cast<const unsigned*>(p); r.y = 0;
            return r;
        }
    };

    int beg = rowptr[n], end = rowptr[n + 1];   // deg >= 1 (self-loop)
    float m = -INFINITY, l = 0.f;

    float4 md_c = meta[beg];
    float4 md_n = meta[min(beg + 1, end - 1)];
    uint2  rx_c = ldxl(__float_as_int(md_c.w));

    for (int j = beg; j < end; j++) {
        uint2 rx_n = ldxl(__float_as_int(md_n.w));       // edge j+1 gather
        float4 md_n2 = meta[min(j + 2, end - 1)];        // meta 2 ahead
        float xl[CPL];
        if constexpr (CPL == 4) {
            unpack2(rx_c.x, xl[0], xl[1]); unpack2(rx_c.y, xl[2], xl[3]);
        } else {
            unpack2(rx_c.x, xl[0], xl[1]);
        }
        float part = 0.f;
        #pragma unroll
        for (int i = 0; i < CPL; i++) {
            float u = fmaf(md_c.x, we0[i],
                      fmaf(md_c.y, we1[i],
                      fmaf(md_c.z, we2[i], xl[i] + xr[i])));
            float lr = fmaxf(u, 0.2f * u);
            part = fmaf(lr, sa[i], part);
        }
        #pragma unroll
        for (int off = GS / 2; off >= 1; off >>= 1)
            part += __shfl_xor(part, off);
        if (__all(part <= m + 8.f)) {       // defer-max common path
            float w = __expf(part - m);
            l += w;
            #pragma unroll
            for (int i = 0; i < CPL; i++) acc[i] = fmaf(w, xl[i], acc[i]);
        } else {                            // rescale path (first edge + rare)
            float mn = fmaxf(m, part);
            float sc = __expf(m - mn);
            float w  = __expf(part - mn);
            l = fmaf(l, sc, w);
            #pragma unroll
            for (int i = 0; i < CPL; i++) acc[i] = fmaf(acc[i], sc, w * xl[i]);
            m = mn;
        }
        md_c = md_n; md_n = md_n2; rx_c = rx_n;
    }

    float inv = 1.f / (l + 1e-16f);
    float o[CPL];
    #pragma unroll
    for (int i = 0; i < CPL; i++) o[i] = acc[i] * inv + bo[cb + i];
    if constexpr (F32OUT) {
        float* q = outf + (size_t)n * HC + cb;
        if constexpr (CPL == 4) {
            *reinterpret_cast<float4*>(q) = make_float4(o[0], o[1], o[2], o[3]);
        } else {
            *reinterpret_cast<float2*>(q) = make_float2(o[0], o[1]);
        }
    } else {
        u16* q = outb + (size_t)n * HC + cb;
        if constexpr (CPL == 4) {
            *reinterpret_cast<uint2*>(q) =
                make_uint2(pack2(o[0], o[1]), pack2(o[2], o[3]));
        } else {
            *reinterpret_cast<unsigned*>(q) = pack2(o[0], o[1]);
        }
    }
}

// ---------------------------------------------------------------- layernorm (bf16 / fp32)

__global__ __launch_bounds__(256) void ln_stats_bf(const u16* __restrict__ x,
                                                   double* __restrict__ stats,
                                                   size_t count) {
    double s = 0.0, s2 = 0.0;
    size_t stride = (size_t)gridDim.x * 256 * 8;
    for (size_t i = ((size_t)blockIdx.x * 256 + threadIdx.x) * 8; i < count; i += stride) {
        uint4 v = *reinterpret_cast<const uint4*>(x + i);
        float f[8];
        unpack2(v.x, f[0], f[1]); unpack2(v.y, f[2], f[3]);
        unpack2(v.z, f[4], f[5]); unpack2(v.w, f[6], f[7]);
        float ps = 0.f, ps2 = 0.f;
        #pragma unroll
        for (int k = 0; k < 8; k++) { ps += f[k]; ps2 += f[k] * f[k]; }
        s += (double)ps; s2 += (double)ps2;
    }
    #pragma unroll
    for (int off = 32; off; off >>= 1) {
        s += __shfl_xor(s, off);
        s2 += __shfl_xor(s2, off);
    }
    __shared__ double wsh[4], wsh2[4];
    int wid = threadIdx.x >> 6, lane = threadIdx.x & 63;
    if (lane == 0) { wsh[wid] = s; wsh2[wid] = s2; }
    __syncthreads();
    if (threadIdx.x == 0) {
        double a = 0.0, b = 0.0;
        for (int w = 0; w < 4; w++) { a += wsh[w]; b += wsh2[w]; }
        atomicAdd(&stats[0], a);
        atomicAdd(&stats[1], b);
    }
}

__global__ __launch_bounds__(256) void ln_apply_elu_bf(u16* __restrict__ x,
                                                       const double* __restrict__ stats,
                                                       const float* __restrict__ w,
                                                       const float* __restrict__ b,
                                                       int F, size_t count) {
    double mu = stats[0] / (double)count;
    double var = stats[1] / (double)count - mu * mu;
    float sd = (float)sqrt(var > 0.0 ? var : 0.0);
    float rs = 1.f / (sd + 1e-5f);
    float muf = (float)mu;
    size_t stride = (size_t)gridDim.x * 256 * 8;
    for (size_t i = ((size_t)blockIdx.x * 256 + threadIdx.x) * 8; i < count; i += stride) {
        uint4 v = *reinterpret_cast<const uint4*>(x + i);
        float f[8];
        unpack2(v.x, f[0], f[1]); unpack2(v.y, f[2], f[3]);
        unpack2(v.z, f[4], f[5]); unpack2(v.w, f[6], f[7]);
        int c = (int)(i & (size_t)(F - 1));
        #pragma unroll
        for (int k = 0; k < 8; k++) {
            float u = (f[k] - muf) * rs * w[c + k] + b[c + k];
            f[k] = u > 0.f ? u : expm1f(u);
        }
        uint4 o = make_uint4(pack2(f[0], f[1]), pack2(f[2], f[3]),
                             pack2(f[4], f[5]), pack2(f[6], f[7]));
        *reinterpret_cast<uint4*>(x + i) = o;
    }
}

__global__ __launch_bounds__(256) void ln_stats_f32(const float* __restrict__ x,
                                                    double* __restrict__ stats,
                                                    size_t count) {
    double s = 0.0, s2 = 0.0;
    size_t stride = (size_t)gridDim.x * 256 * 4;
    for (size_t i = ((size_t)blockIdx.x * 256 + threadIdx.x) * 4; i < count; i += stride) {
        float4 v = *reinterpret_cast<const float4*>(x + i);
        s += (double)v.x + (double)v.y + (double)v.z + (double)v.w;
        s2 += (double)v.x * v.x + (double)v.y * v.y +
              (double)v.z * v.z + (double)v.w * v.w;
    }
    #pragma unroll
    for (int off = 32; off; off >>= 1) {
        s += __shfl_xor(s, off);
        s2 += __shfl_xor(s2, off);
    }
    __shared__ double wsh[4], wsh2[4];
    int wid = threadIdx.x >> 6, lane = threadIdx.x & 63;
    if (lane == 0) { wsh[wid] = s; wsh2[wid] = s2; }
    __syncthreads();
    if (threadIdx.x == 0) {
        double a = 0.0, b = 0.0;
        for (int w = 0; w < 4; w++) { a += wsh[w]; b += wsh2[w]; }
        atomicAdd(&stats[0], a);
        atomicAdd(&stats[1], b);
    }
}

__global__ __launch_bounds__(256) void ln_apply_elu_f32(float* __restrict__ x,
                                                        const double* __restrict__ stats,
                                                        const float* __restrict__ w,
                                                        const float* __restrict__ b,
                                                        int F, size_t count) {
    double mu = stats[0] / (double)count;
    double var = stats[1] / (double)count - mu * mu;
    float sd = (float)sqrt(var > 0.0 ? var : 0.0);
    float rs = 1.f / (sd + 1e-5f);
    float muf = (float)mu;
    for (size_t i = (size_t)blockIdx.x * 256 + threadIdx.x; i < count;
         i += (size_t)gridDim.x * 256) {
        int c = (int)(i & (size_t)(F - 1));
        float v = (x[i] - muf) * rs * w[c] + b[c];
        x[i] = v > 0.f ? v : expm1f(v);
    }
}

// ---------------------------------------------------------------- pooling

__global__ __launch_bounds__(256) void pool_kernel(const float* __restrict__ h,
                                                   const int* __restrict__ goff,
                                                   float* __restrict__ out) {
    __shared__ float sh[128], mh[128];
    int g = blockIdx.x;
    int s = goff[g], e = goff[g + 1];
    int tid = threadIdx.x;
    int c = tid & 127, part = tid >> 7;
    float sum = 0.f, mx = -INFINITY;
    for (int n = s + part; n < e; n += 2) {
        float v = h[(size_t)n * 128 + c];
        sum += v;
        mx = fmaxf(mx, v);
    }
    if (part == 1) { sh[c] = sum; mh[c] = mx; }
    __syncthreads();
    if (part == 0) {
        if (e - s > 1) { sum += sh[c]; mx = fmaxf(mx, mh[c]); }
        int cnt = e - s;
        out[g * 256 + c] = cnt > 0 ? sum / (float)cnt : 0.f;
        out[g * 256 + 128 + c] = cnt > 0 ? mx : 0.f;
    }
}

// ---------------------------------------------------------------- launch

extern "C" void kernel_launch(void* const* d_in, const int* in_sizes, int n_in,
                              void* d_out, int out_size, void* d_ws, size_t ws_size,
                              hipStream_t stream) {
    const int N = N_NODES, E = N_EDGES, G = N_GRAPHS, E2 = E2_TOTAL;
    const float* x = (const float*)d_in[0];
    const int* ei = (const int*)d_in[1];
    const float* eattr = (const float*)d_in[2];
    const int* batch = (const int*)d_in[3];
    auto P = [&](int l, int k) { return (const float*)d_in[4 + l * 9 + k]; };
    // k: 0=Wl 1=bl 2=Wr 3=br 4=We 5=att 6=bo 7=lnw 8=lnb

    char* w = (char*)d_ws;
    size_t off = 0;
    auto alloc = [&](size_t bytes) -> void* {
        void* p = w + off;
        off += (bytes + 255) & ~(size_t)255;
        return p;
    };
    u16* Xa = (u16*)alloc((size_t)N * 512 * 2);      // XL per layer
    u16* Xb = (u16*)alloc((size_t)N * 512 * 2);      // XR per layer
    u16* Xc = (u16*)alloc((size_t)N * 512 * 2);      // h (post-LN+ELU) per layer
    float* H3f = (float*)alloc((size_t)N * 128 * 4); // layer-3 output fp32
    float4* meta = (float4*)alloc((size_t)E2 * 16);  // CSR-ordered {ea, src}
    u16* WtL = (u16*)alloc((size_t)512 * 256 * 2);
    u16* WtR = (u16*)alloc((size_t)512 * 256 * 2);
    int* rowptr = (int*)alloc((size_t)(N + 1) * 4);
    int* cursor = (int*)alloc((size_t)N * 4);
    int* deg = (int*)alloc((size_t)N * 4);
    float* lattr = (float*)alloc((size_t)N * 3 * 4);
    double* stats = (double*)alloc(6 * 8);
    int* goff = (int*)alloc((size_t)(G + 1) * 4);
    (void)ws_size; (void)n_in; (void)in_sizes; (void)out_size;

    hipMemsetAsync(deg, 0, (size_t)N * 4, stream);
    hipMemsetAsync(lattr, 0, (size_t)N * 3 * 4, stream);
    hipMemsetAsync(stats, 0, 6 * 8, stream);

    deg_kernel<<<(E + 255) / 256, 256, 0, stream>>>(ei, eattr, deg, lattr, E);
    loopattr_kernel<<<(N + 255) / 256, 256, 0, stream>>>(deg, lattr, N);
    scan_kernel<<<1, 1024, 0, stream>>>(deg, rowptr, N);
    copy_kernel<<<(N + 255) / 256, 256, 0, stream>>>(rowptr, cursor, N);
    fill_kernel<<<(E2 + 255) / 256, 256, 0, stream>>>(ei, eattr, lattr, cursor,
                                                      meta, E, E2);
    goff_kernel<<<1, 128, 0, stream>>>(batch, goff, N, G);

    // -------- layer 1 (din=8, H=4, HC=512): 2 waves per node
    xw8_kernel<<<(N + 63) / 64, 256, 0, stream>>>(x, P(0, 0), P(0, 1), Xa, N);
    xw8_kernel<<<(N + 63) / 64, 256, 0, stream>>>(x, P(0, 2), P(0, 3), Xb, N);
    attn_wave<512, 2, false><<<(N * 2 + 3) / 4, 256, 0, stream>>>(
        rowptr, meta, Xa, Xb, P(0, 4), P(0, 5), P(0, 6), nullptr, Xc, N);
    ln_stats_bf<<<1024, 256, 0, stream>>>(Xc, stats + 0, (size_t)N * 512);
    ln_apply_elu_bf<<<1024, 256, 0, stream>>>(Xc, stats + 0, P(0, 7), P(0, 8), 512,
                                              (size_t)N * 512);

    // -------- layer 2 (din=512, H=2, HC=256)
    {
        dim3 tg(512 / 64, 256 / 64);
        wt_kernel<<<tg, 256, 0, stream>>>(P(1, 0), WtL, 512, 256);
        wt_kernel<<<tg, 256, 0, stream>>>(P(1, 2), WtR, 512, 256);
        dim3 gg((N + 127) / 128, 2);
        gemm_mfma<<<gg, 256, 0, stream>>>(Xc, WtL, P(1, 1), Xa, N, 512, 256);
        gemm_mfma<<<gg, 256, 0, stream>>>(Xc, WtR, P(1, 3), Xb, N, 512, 256);
    }
    attn_wave<256, 1, false><<<(N + 3) / 4, 256, 0, stream>>>(
        rowptr, meta, Xa, Xb, P(1, 4), P(1, 5), P(1, 6), nullptr, Xc, N);
    ln_stats_bf<<<1024, 256, 0, stream>>>(Xc, stats + 2, (size_t)N * 256);
    ln_apply_elu_bf<<<1024, 256, 0, stream>>>(Xc, stats + 2, P(1, 7), P(1, 8), 256,
                                              (size_t)N * 256);

    // -------- layer 3 (din=256, H=1, HC=128)
    {
        dim3 tg(256 / 64, 128 / 64);
        wt_kernel<<<tg, 256, 0, stream>>>(P(2, 0), WtL, 256, 128);
        wt_kernel<<<tg, 256, 0, stream>>>(P(2, 2), WtR, 256, 128);
        dim3 gg((N + 127) / 128, 1);
        gemm_mfma<<<gg, 256, 0, stream>>>(Xc, WtL, P(2, 1), Xa, N, 256, 128);
        gemm_mfma<<<gg, 256, 0, stream>>>(Xc, WtR, P(2, 3), Xb, N, 256, 128);
    }
    attn_wave<128, 1, true><<<(N + 3) / 4, 256, 0, stream>>>(
        rowptr, meta, Xa, Xb, P(2, 4), P(2, 5), P(2, 6), H3f, nullptr, N);
    ln_stats_f32<<<1024, 256, 0, stream>>>(H3f, stats + 4, (size_t)N * 128);
    ln_apply_elu_f32<<<1024, 256, 0, stream>>>(H3f, stats + 4, P(2, 7), P(2, 8), 128,
                                               (size_t)N * 128);

    // -------- pooling
    pool_kernel<<<G, 256, 0, stream>>>(H3f, goff, (float*)d_out);
}

// Round 7
// 996.893 us; speedup vs baseline: 3.7356x; 1.1347x over previous
//
#include <hip/hip_runtime.h>
#include <hip/hip_bf16.h>
#include <math.h>

#define N_NODES 50000
#define N_EDGES 800000
#define N_GRAPHS 64
#define E2_TOTAL (N_EDGES + N_NODES)

typedef unsigned short u16;
typedef __attribute__((ext_vector_type(8))) short s16x8;
typedef __attribute__((ext_vector_type(4))) float f32x4;

__device__ __forceinline__ u16 f2bf(float f) {
    unsigned u = __float_as_uint(f);
    u += 0x7fffu + ((u >> 16) & 1u);   // round-to-nearest-even
    return (u16)(u >> 16);
}
__device__ __forceinline__ float bf2f(u16 s) {
    return __uint_as_float((unsigned)s << 16);
}
__device__ __forceinline__ void unpack2(unsigned v, float& a, float& b) {
    a = __uint_as_float(v << 16);
    b = __uint_as_float(v & 0xffff0000u);
}
__device__ __forceinline__ unsigned pack2(float a, float b) {
    return (unsigned)f2bf(a) | ((unsigned)f2bf(b) << 16);
}

// ---------------------------------------------------------------- CSR build

__global__ __launch_bounds__(256) void deg_kernel(const int* __restrict__ ei,
                                                  const float* __restrict__ eattr,
                                                  int* __restrict__ deg,
                                                  float* __restrict__ asum, int E) {
    int e = blockIdx.x * 256 + threadIdx.x;
    if (e >= E) return;
    int dst = ei[E + e];
    atomicAdd(&deg[dst], 1);
    atomicAdd(&asum[dst * 3 + 0], eattr[e * 3 + 0]);
    atomicAdd(&asum[dst * 3 + 1], eattr[e * 3 + 1]);
    atomicAdd(&asum[dst * 3 + 2], eattr[e * 3 + 2]);
}

__global__ __launch_bounds__(256) void loopattr_kernel(const int* __restrict__ deg,
                                                       float* __restrict__ asum, int N) {
    int n = blockIdx.x * 256 + threadIdx.x;
    if (n >= N) return;
    float inv = 1.0f / (float)max(deg[n], 1);
    asum[n * 3 + 0] *= inv;
    asum[n * 3 + 1] *= inv;
    asum[n * 3 + 2] *= inv;
}

// exclusive scan of (deg+1); 4 elements per thread, single block of 1024
__global__ __launch_bounds__(1024) void scan_kernel(const int* __restrict__ deg,
                                                    int* __restrict__ rowptr, int N) {
    __shared__ int wsum[16];
    __shared__ int carry_s;
    int tid = threadIdx.x, lane = tid & 63, wid = tid >> 6;
    if (tid == 0) carry_s = 0;
    __syncthreads();
    for (int base = 0; base < N; base += 4096) {
        int i0 = base + tid * 4;
        int d0 = (i0 + 0 < N) ? deg[i0 + 0] + 1 : 0;
        int d1 = (i0 + 1 < N) ? deg[i0 + 1] + 1 : 0;
        int d2 = (i0 + 2 < N) ? deg[i0 + 2] + 1 : 0;
        int d3 = (i0 + 3 < N) ? deg[i0 + 3] + 1 : 0;
        int v = d0 + d1 + d2 + d3;
        int x = v;
        #pragma unroll
        for (int off = 1; off < 64; off <<= 1) {
            int t = __shfl_up(x, off);
            if (lane >= off) x += t;
        }
        if (lane == 63) wsum[wid] = x;
        __syncthreads();
        if (wid == 0) {
            int y = (lane < 16) ? wsum[lane] : 0;
            #pragma unroll
            for (int off = 1; off < 16; off <<= 1) {
                int t = __shfl_up(y, off);
                if (lane >= off) y += t;
            }
            if (lane < 16) wsum[lane] = y;
        }
        __syncthreads();
        int woff = (wid > 0) ? wsum[wid - 1] : 0;
        int excl = carry_s + woff + x - v;
        if (i0 + 0 < N) rowptr[i0 + 0] = excl;
        if (i0 + 1 < N) rowptr[i0 + 1] = excl + d0;
        if (i0 + 2 < N) rowptr[i0 + 2] = excl + d0 + d1;
        if (i0 + 3 < N) rowptr[i0 + 3] = excl + d0 + d1 + d2;
        __syncthreads();
        if (tid == 1023) carry_s += wsum[15];
        __syncthreads();
    }
    if (threadIdx.x == 0) rowptr[N] = carry_s;
}

__global__ __launch_bounds__(256) void copy_kernel(const int* __restrict__ a,
                                                   int* __restrict__ b, int N) {
    int n = blockIdx.x * 256 + threadIdx.x;
    if (n < N) b[n] = a[n];
}

// CSR fill: meta[pos] = {ea0, ea1, ea2, src-as-float-bits}
__global__ __launch_bounds__(256) void fill_kernel(const int* __restrict__ ei,
                                                   const float* __restrict__ eattr,
                                                   const float* __restrict__ lattr,
                                                   int* __restrict__ cursor,
                                                   float4* __restrict__ meta,
                                                   int E, int E2) {
    int e = blockIdx.x * 256 + threadIdx.x;
    if (e >= E2) return;
    int src, dst;
    float a0, a1, a2;
    if (e < E) {
        src = ei[e]; dst = ei[E + e];
        a0 = eattr[(size_t)e * 3 + 0];
        a1 = eattr[(size_t)e * 3 + 1];
        a2 = eattr[(size_t)e * 3 + 2];
    } else {
        src = e - E; dst = src;
        a0 = lattr[(size_t)dst * 3 + 0];
        a1 = lattr[(size_t)dst * 3 + 1];
        a2 = lattr[(size_t)dst * 3 + 2];
    }
    int pos = atomicAdd(&cursor[dst], 1);
    meta[pos] = make_float4(a0, a1, a2, __int_as_float(src));
}

// goff via binary search (batch is sorted)
__global__ __launch_bounds__(128) void goff_kernel(const int* __restrict__ batch,
                                                   int* __restrict__ goff, int N, int G) {
    int g = threadIdx.x;
    if (g > G) return;
    int lo = 0, hi = N;
    while (lo < hi) {
        int mid = (lo + hi) >> 1;
        if (batch[mid] < g) lo = mid + 1; else hi = mid;
    }
    goff[g] = lo;
}

// ---------------------------------------------------------------- X1 = x@W+b (din=8), both L and R -> bf16

__global__ __launch_bounds__(256) void xw8_dual(const float* __restrict__ x,
                                                const float* __restrict__ Wl,
                                                const float* __restrict__ bl,
                                                const float* __restrict__ Wr,
                                                const float* __restrict__ br,
                                                u16* __restrict__ Xa,
                                                u16* __restrict__ Xb, int N) {
    __shared__ float sWl[8 * 512], sWr[8 * 512];
    __shared__ float sbl[512], sbr[512];
    __shared__ float sx[64][8];
    int tid = threadIdx.x;
    int nb = blockIdx.x * 64;
    for (int i = tid; i < 8 * 512; i += 256) { sWl[i] = Wl[i]; sWr[i] = Wr[i]; }
    for (int i = tid; i < 512; i += 256) { sbl[i] = bl[i]; sbr[i] = br[i]; }
    for (int i = tid; i < 64 * 8; i += 256) {
        int j = i >> 3, k = i & 7;
        int n = nb + j;
        sx[j][k] = (n < N) ? x[(size_t)n * 8 + k] : 0.f;
    }
    __syncthreads();
    for (int it = 0; it < 64; it++) {
        int i = tid + it * 256;
        int j = i >> 8, c2 = (i & 255) * 2;
        int n = nb + j;
        if (n < N) {
            float l0 = sbl[c2], l1 = sbl[c2 + 1];
            float r0 = sbr[c2], r1 = sbr[c2 + 1];
            #pragma unroll
            for (int k = 0; k < 8; k++) {
                float xv = sx[j][k];
                l0 += xv * sWl[k * 512 + c2];
                l1 += xv * sWl[k * 512 + c2 + 1];
                r0 += xv * sWr[k * 512 + c2];
                r1 += xv * sWr[k * 512 + c2 + 1];
            }
            *reinterpret_cast<unsigned*>(Xa + (size_t)n * 512 + c2) = pack2(l0, l1);
            *reinterpret_cast<unsigned*>(Xb + (size_t)n * 512 + c2) = pack2(r0, r1);
        }
    }
}

// ---------------------------------------------------------------- W -> Wt bf16 transpose (dual via blockIdx.z)

__global__ __launch_bounds__(256) void wt_dual(const float* __restrict__ WL,
                                               const float* __restrict__ WR,
                                               u16* __restrict__ WtL,
                                               u16* __restrict__ WtR, int K, int M) {
    const float* W = blockIdx.z ? WR : WL;
    u16* Wt = blockIdx.z ? WtR : WtL;
    __shared__ u16 t[64][65];
    int kb = blockIdx.x * 64, mb = blockIdx.y * 64;
    int tid = threadIdx.x;
    for (int i = tid; i < 64 * 64; i += 256) {
        int k = i >> 6, m = i & 63;
        t[m][k] = f2bf(W[(size_t)(kb + k) * M + mb + m]);
    }
    __syncthreads();
    for (int i = tid; i < 64 * 64; i += 256) {
        int m = i >> 6, k = i & 63;
        Wt[(size_t)(mb + m) * K + kb + k] = t[m][k];
    }
}

// ---------------------------------------------------------------- MFMA GEMM (bf16), dual via blockIdx.z

__global__ __launch_bounds__(256) void gemm_dual(const u16* __restrict__ A,
                                                 const u16* __restrict__ BtL,
                                                 const u16* __restrict__ BtR,
                                                 const float* __restrict__ biasL,
                                                 const float* __restrict__ biasR,
                                                 u16* __restrict__ YL,
                                                 u16* __restrict__ YR,
                                                 int N, int K, int M) {
    const u16* Bt = blockIdx.z ? BtR : BtL;
    const float* bias = blockIdx.z ? biasR : biasL;
    u16* Y = blockIdx.z ? YR : YL;
    constexpr int BM = 128, BK = 64;
    __shared__ u16 As[BM][BK + 8];
    __shared__ u16 Bs[BM][BK + 8];
    int tid = threadIdx.x;
    int wid = tid >> 6, lane = tid & 63;
    int wm = (wid >> 1) * 64, wn = (wid & 1) * 64;
    int bm = blockIdx.x * BM, bn = blockIdx.y * BM;
    int l15 = lane & 15, l4 = lane >> 4;
    f32x4 acc[4][4] = {};
    int sr = tid >> 3;
    int sc = (tid & 7) * 8;

    for (int k0 = 0; k0 < K; k0 += BK) {
        #pragma unroll
        for (int p = 0; p < 4; p++) {
            int r = p * 32 + sr;
            int grow = bm + r;
            uint4 av = make_uint4(0, 0, 0, 0);
            if (grow < N)
                av = *reinterpret_cast<const uint4*>(A + (size_t)grow * K + k0 + sc);
            *reinterpret_cast<uint4*>(&As[r][sc]) = av;
            uint4 bv = *reinterpret_cast<const uint4*>(Bt + (size_t)(bn + r) * K + k0 + sc);
            *reinterpret_cast<uint4*>(&Bs[r][sc]) = bv;
        }
        __syncthreads();
        #pragma unroll
        for (int kk = 0; kk < 2; kk++) {
            int kof = kk * 32 + l4 * 8;
            s16x8 af[4], bfr[4];
            #pragma unroll
            for (int i = 0; i < 4; i++) {
                af[i]  = *reinterpret_cast<const s16x8*>(&As[wm + i * 16 + l15][kof]);
                bfr[i] = *reinterpret_cast<const s16x8*>(&Bs[wn + i * 16 + l15][kof]);
            }
            #pragma unroll
            for (int i = 0; i < 4; i++)
                #pragma unroll
                for (int j = 0; j < 4; j++)
                    acc[i][j] = __builtin_amdgcn_mfma_f32_16x16x32_bf16(
                        af[i], bfr[j], acc[i][j], 0, 0, 0);
        }
        __syncthreads();
    }
    #pragma unroll
    for (int i = 0; i < 4; i++) {
        #pragma unroll
        for (int j = 0; j < 4; j++) {
            int col = bn + wn + j * 16 + l15;
            float bv = bias[col];
            #pragma unroll
            for (int r = 0; r < 4; r++) {
                int row = bm + wm + i * 16 + l4 * 4 + r;
                if (row < N)
                    Y[(size_t)row * M + col] = f2bf(acc[i][j][r] + bv);
            }
        }
    }
}

// ---------------------------------------------------------------- wave-per-node GATv2
// Scalarized edge loop (s_load meta, SGPR gather base), 2 edges/iter with
// 2-ahead prefetch, defer-max softmax, fused LN-stats bucket atomics.

template <int HC, int SPLIT, bool F32OUT>
__global__ __launch_bounds__(256) void attn_wave(
    const int* __restrict__ rowptr, const float4* __restrict__ meta,
    const u16* __restrict__ XLbf, const u16* __restrict__ XRbf,
    const float* __restrict__ We, const float* __restrict__ att,
    const float* __restrict__ bo, float* __restrict__ outf,
    u16* __restrict__ outb, double* __restrict__ sbuck, int N) {
    constexpr int CW  = HC / SPLIT;   // channels per wave
    constexpr int CPL = CW / 64;      // 4 or 2
    constexpr int GS  = 128 / CPL;    // lanes per head group (32 or 64)
    int gw = blockIdx.x * 4 + (threadIdx.x >> 6);
    int lane = threadIdx.x & 63;
    int n = gw / SPLIT;
    int sub = gw - n * SPLIT;
    if (n >= N) return;
    int cb = sub * CW + lane * CPL;

    float xr[CPL], we0[CPL], we1[CPL], we2[CPL], sa[CPL], acc[CPL];
    #pragma unroll
    for (int i = 0; i < CPL; i++) {
        we0[i] = We[cb + i];
        we1[i] = We[HC + cb + i];
        we2[i] = We[2 * HC + cb + i];
        sa[i]  = att[cb + i];
        acc[i] = 0.f;
    }
    {
        const u16* p = XRbf + (size_t)n * HC + cb;
        if constexpr (CPL == 4) {
            uint2 r = *reinterpret_cast<const uint2*>(p);
            unpack2(r.x, xr[0], xr[1]); unpack2(r.y, xr[2], xr[3]);
        } else {
            unsigned r = *reinterpret_cast<const unsigned*>(p);
            unpack2(r, xr[0], xr[1]);
        }
    }

    auto ldxl = [&](int src) -> uint2 {
        const u16* p = XLbf + (size_t)src * HC + cb;
        if constexpr (CPL == 4) {
            return *reinterpret_cast<const uint2*>(p);
        } else {
            uint2 r; r.x = *reinterpret_cast<const unsigned*>(p); r.y = 0;
            return r;
        }
    };

    int beg = __builtin_amdgcn_readfirstlane(rowptr[n]);
    int end = __builtin_amdgcn_readfirstlane(rowptr[n + 1]);
    int e1 = end - 1;
    float m = -INFINITY, l = 0.f;

    float4 mdA = meta[beg];
    float4 mdB = meta[min(beg + 1, e1)];
    int sA = __builtin_amdgcn_readfirstlane(__float_as_int(mdA.w));
    int sB = __builtin_amdgcn_readfirstlane(__float_as_int(mdB.w));
    uint2 rA = ldxl(sA), rB = ldxl(sB);

    for (int j = beg; j < end; j += 2) {
        int jn = min(j + 2, e1);
        float4 mdA_n = meta[jn];
        float4 mdB_n = meta[min(j + 3, e1)];
        int sAn = __builtin_amdgcn_readfirstlane(__float_as_int(mdA_n.w));
        int sBn = __builtin_amdgcn_readfirstlane(__float_as_int(mdB_n.w));
        uint2 rA_n = ldxl(sAn), rB_n = ldxl(sBn);

        float xl0[CPL], xl1[CPL];
        if constexpr (CPL == 4) {
            unpack2(rA.x, xl0[0], xl0[1]); unpack2(rA.y, xl0[2], xl0[3]);
            unpack2(rB.x, xl1[0], xl1[1]); unpack2(rB.y, xl1[2], xl1[3]);
        } else {
            unpack2(rA.x, xl0[0], xl0[1]);
            unpack2(rB.x, xl1[0], xl1[1]);
        }
        float p0 = 0.f, p1 = 0.f;
        #pragma unroll
        for (int i = 0; i < CPL; i++) {
            float u0 = fmaf(mdA.x, we0[i],
                       fmaf(mdA.y, we1[i],
                       fmaf(mdA.z, we2[i], xl0[i] + xr[i])));
            float u1 = fmaf(mdB.x, we0[i],
                       fmaf(mdB.y, we1[i],
                       fmaf(mdB.z, we2[i], xl1[i] + xr[i])));
            p0 = fmaf(fmaxf(u0, 0.2f * u0), sa[i], p0);
            p1 = fmaf(fmaxf(u1, 0.2f * u1), sa[i], p1);
        }
        #pragma unroll
        for (int off = GS / 2; off >= 1; off >>= 1) {
            p0 += __shfl_xor(p0, off);
            p1 += __shfl_xor(p1, off);
        }
        if (j + 1 > e1) p1 = -INFINITY;   // odd tail: w1 = 0
        float hi = fmaxf(p0, p1);
        if (__all(hi <= m + 8.f)) {        // defer-max common path
            float w0 = __expf(p0 - m), w1 = __expf(p1 - m);
            l += w0 + w1;
            #pragma unroll
            for (int i = 0; i < CPL; i++)
                acc[i] = fmaf(w0, xl0[i], fmaf(w1, xl1[i], acc[i]));
        } else {                           // rescale path (first iter + rare)
            float mn = fmaxf(m, hi);
            float sc = __expf(m - mn);
            float w0 = __expf(p0 - mn), w1 = __expf(p1 - mn);
            l = fmaf(l, sc, w0 + w1);
            #pragma unroll
            for (int i = 0; i < CPL; i++)
                acc[i] = fmaf(acc[i], sc, fmaf(w0, xl0[i], w1 * xl1[i]));
            m = mn;
        }
        mdA = mdA_n; mdB = mdB_n; rA = rA_n; rB = rB_n;
    }

    float inv = 1.f / (l + 1e-16f);
    float o[CPL];
    float s = 0.f, s2 = 0.f;
    #pragma unroll
    for (int i = 0; i < CPL; i++) {
        o[i] = acc[i] * inv + bo[cb + i];
        s += o[i]; s2 += o[i] * o[i];
    }
    if constexpr (F32OUT) {
        float* q = outf + (size_t)n * HC + cb;
        if constexpr (CPL == 4) {
            *reinterpret_cast<float4*>(q) = make_float4(o[0], o[1], o[2], o[3]);
        } else {
            *reinterpret_cast<float2*>(q) = make_float2(o[0], o[1]);
        }
    } else {
        u16* q = outb + (size_t)n * HC + cb;
        if constexpr (CPL == 4) {
            *reinterpret_cast<uint2*>(q) =
                make_uint2(pack2(o[0], o[1]), pack2(o[2], o[3]));
        } else {
            *reinterpret_cast<unsigned*>(q) = pack2(o[0], o[1]);
        }
    }
    // fused LN-stats partials
    #pragma unroll
    for (int off = 32; off; off >>= 1) {
        s += __shfl_xor(s, off);
        s2 += __shfl_xor(s2, off);
    }
    if (lane == 0) {
        double* bk = sbuck + (size_t)(blockIdx.x & 511) * 2;
        atomicAdd(bk, (double)s);
        atomicAdd(bk + 1, (double)s2);
    }
}

// ---------------------------------------------------------------- LN finalize: 512 buckets -> {mu, rs}

__global__ __launch_bounds__(256) void ln_finalize(const double* __restrict__ buck,
                                                   float2* __restrict__ lnp,
                                                   double count) {
    int t = threadIdx.x;
    double s  = buck[t * 2]     + buck[(t + 256) * 2];
    double s2 = buck[t * 2 + 1] + buck[(t + 256) * 2 + 1];
    #pragma unroll
    for (int off = 32; off; off >>= 1) {
        s += __shfl_xor(s, off);
        s2 += __shfl_xor(s2, off);
    }
    __shared__ double a[4], b[4];
    int wid = t >> 6, lane = t & 63;
    if (lane == 0) { a[wid] = s; b[wid] = s2; }
    __syncthreads();
    if (t == 0) {
        double S = a[0] + a[1] + a[2] + a[3];
        double S2 = b[0] + b[1] + b[2] + b[3];
        double mu = S / count;
        double var = S2 / count - mu * mu;
        float sd = (float)sqrt(var > 0.0 ? var : 0.0);
        lnp->x = (float)mu;
        lnp->y = 1.f / (sd + 1e-5f);
    }
}

// ---------------------------------------------------------------- LN apply + ELU (bf16 in-place)

__global__ __launch_bounds__(256) void ln_apply_elu_bf(u16* __restrict__ x,
                                                       const float2* __restrict__ lnp,
                                                       const float* __restrict__ w,
                                                       const float* __restrict__ b,
                                                       int F, size_t count) {
    float2 lp = *lnp;
    float muf = lp.x, rs = lp.y;
    size_t stride = (size_t)gridDim.x * 256 * 8;
    for (size_t i = ((size_t)blockIdx.x * 256 + threadIdx.x) * 8; i < count; i += stride) {
        uint4 v = *reinterpret_cast<const uint4*>(x + i);
        float f[8];
        unpack2(v.x, f[0], f[1]); unpack2(v.y, f[2], f[3]);
        unpack2(v.z, f[4], f[5]); unpack2(v.w, f[6], f[7]);
        int c = (int)(i & (size_t)(F - 1));
        #pragma unroll
        for (int k = 0; k < 8; k++) {
            float u = (f[k] - muf) * rs * w[c + k] + b[c + k];
            f[k] = u > 0.f ? u : expm1f(u);
        }
        uint4 o = make_uint4(pack2(f[0], f[1]), pack2(f[2], f[3]),
                             pack2(f[4], f[5]), pack2(f[6], f[7]));
        *reinterpret_cast<uint4*>(x + i) = o;
    }
}

// ---------------------------------------------------------------- pooling with fused LN+ELU (layer 3)

__global__ __launch_bounds__(256) void pool_ln(const float* __restrict__ h,
                                               const int* __restrict__ goff,
                                               const float2* __restrict__ lnp,
                                               const float* __restrict__ lw,
                                               const float* __restrict__ lb,
                                               float* __restrict__ out) {
    __shared__ float sh[128], mh[128];
    float2 lp = *lnp;
    int g = blockIdx.x;
    int s = goff[g], e = goff[g + 1];
    int tid = threadIdx.x;
    int c = tid & 127, part = tid >> 7;
    float wc = lw[c] * lp.y, bc = lb[c];
    float sum = 0.f, mx = -INFINITY;
    for (int n = s + part; n < e; n += 2) {
        float v = (h[(size_t)n * 128 + c] - lp.x) * wc + bc;
        v = v > 0.f ? v : expm1f(v);
        sum += v;
        mx = fmaxf(mx, v);
    }
    if (part == 1) { sh[c] = sum; mh[c] = mx; }
    __syncthreads();
    if (part == 0) {
        if (e - s > 1) { sum += sh[c]; mx = fmaxf(mx, mh[c]); }
        int cnt = e - s;
        out[g * 256 + c] = cnt > 0 ? sum / (float)cnt : 0.f;
        out[g * 256 + 128 + c] = cnt > 0 ? mx : 0.f;
    }
}

// ---------------------------------------------------------------- launch

extern "C" void kernel_launch(void* const* d_in, const int* in_sizes, int n_in,
                              void* d_out, int out_size, void* d_ws, size_t ws_size,
                              hipStream_t stream) {
    const int N = N_NODES, E = N_EDGES, G = N_GRAPHS, E2 = E2_TOTAL;
    const float* x = (const float*)d_in[0];
    const int* ei = (const int*)d_in[1];
    const float* eattr = (const float*)d_in[2];
    const int* batch = (const int*)d_in[3];
    auto P = [&](int l, int k) { return (const float*)d_in[4 + l * 9 + k]; };
    // k: 0=Wl 1=bl 2=Wr 3=br 4=We 5=att 6=bo 7=lnw 8=lnb

    char* w = (char*)d_ws;
    size_t off = 0;
    auto alloc = [&](size_t bytes) -> void* {
        void* p = w + off;
        off += (bytes + 255) & ~(size_t)255;
        return p;
    };
    u16* Xa = (u16*)alloc((size_t)N * 512 * 2);      // XL per layer
    u16* Xb = (u16*)alloc((size_t)N * 512 * 2);      // XR per layer
    u16* Xc = (u16*)alloc((size_t)N * 512 * 2);      // h per layer
    float* H3f = (float*)alloc((size_t)N * 128 * 4); // layer-3 attn out fp32
    float4* meta = (float4*)alloc((size_t)E2 * 16);  // CSR-ordered {ea, src}
    u16* WtL = (u16*)alloc((size_t)512 * 256 * 2);
    u16* WtR = (u16*)alloc((size_t)512 * 256 * 2);
    int* rowptr = (int*)alloc((size_t)(N + 1) * 4);
    int* cursor = (int*)alloc((size_t)N * 4);
    int* goff = (int*)alloc((size_t)(G + 1) * 4);
    float2* lnp = (float2*)alloc(3 * sizeof(float2));
    // zero-initialized region: [zs, ze)
    size_t zs = off;
    int* deg = (int*)alloc((size_t)N * 4);
    float* lattr = (float*)alloc((size_t)N * 3 * 4);
    double* b1 = (double*)alloc(512 * 2 * 8);
    double* b2 = (double*)alloc(512 * 2 * 8);
    double* b3 = (double*)alloc(512 * 2 * 8);
    size_t ze = off;
    (void)ws_size; (void)n_in; (void)in_sizes; (void)out_size;

    hipMemsetAsync(w + zs, 0, ze - zs, stream);

    deg_kernel<<<(E + 255) / 256, 256, 0, stream>>>(ei, eattr, deg, lattr, E);
    loopattr_kernel<<<(N + 255) / 256, 256, 0, stream>>>(deg, lattr, N);
    scan_kernel<<<1, 1024, 0, stream>>>(deg, rowptr, N);
    copy_kernel<<<(N + 255) / 256, 256, 0, stream>>>(rowptr, cursor, N);
    fill_kernel<<<(E2 + 255) / 256, 256, 0, stream>>>(ei, eattr, lattr, cursor,
                                                      meta, E, E2);
    goff_kernel<<<1, 128, 0, stream>>>(batch, goff, N, G);

    // -------- layer 1 (din=8, H=4, HC=512): 2 waves per node
    xw8_dual<<<(N + 63) / 64, 256, 0, stream>>>(x, P(0, 0), P(0, 1), P(0, 2), P(0, 3),
                                                Xa, Xb, N);
    attn_wave<512, 2, false><<<(N * 2 + 3) / 4, 256, 0, stream>>>(
        rowptr, meta, Xa, Xb, P(0, 4), P(0, 5), P(0, 6), nullptr, Xc, b1, N);
    ln_finalize<<<1, 256, 0, stream>>>(b1, lnp + 0, (double)N * 512.0);
    ln_apply_elu_bf<<<1024, 256, 0, stream>>>(Xc, lnp + 0, P(0, 7), P(0, 8), 512,
                                              (size_t)N * 512);

    // -------- layer 2 (din=512, H=2, HC=256)
    {
        dim3 tg(512 / 64, 256 / 64, 2);
        wt_dual<<<tg, 256, 0, stream>>>(P(1, 0), P(1, 2), WtL, WtR, 512, 256);
        dim3 gg((N + 127) / 128, 2, 2);
        gemm_dual<<<gg, 256, 0, stream>>>(Xc, WtL, WtR, P(1, 1), P(1, 3),
                                          Xa, Xb, N, 512, 256);
    }
    attn_wave<256, 1, false><<<(N + 3) / 4, 256, 0, stream>>>(
        rowptr, meta, Xa, Xb, P(1, 4), P(1, 5), P(1, 6), nullptr, Xc, b2, N);
    ln_finalize<<<1, 256, 0, stream>>>(b2, lnp + 1, (double)N * 256.0);
    ln_apply_elu_bf<<<1024, 256, 0, stream>>>(Xc, lnp + 1, P(1, 7), P(1, 8), 256,
                                              (size_t)N * 256);

    // -------- layer 3 (din=256, H=1, HC=128)
    {
        dim3 tg(256 / 64, 128 / 64, 2);
        wt_dual<<<tg, 256, 0, stream>>>(P(2, 0), P(2, 2), WtL, WtR, 256, 128);
        dim3 gg((N + 127) / 128, 1, 2);
        gemm_dual<<<gg, 256, 0, stream>>>(Xc, WtL, WtR, P(2, 1), P(2, 3),
                                          Xa, Xb, N, 256, 128);
    }
    attn_wave<128, 1, true><<<(N + 3) / 4, 256, 0, stream>>>(
        rowptr, meta, Xa, Xb, P(2, 4), P(2, 5), P(2, 6), H3f, nullptr, b3, N);
    ln_finalize<<<1, 256, 0, stream>>>(b3, lnp + 2, (double)N * 128.0);

    // -------- pooling with fused LN+ELU
    pool_ln<<<G, 256, 0, stream>>>(H3f, goff, lnp + 2, P(2, 7), P(2, 8),
                                   (float*)d_out);
}